// Round 10
// baseline (405.130 us; speedup 1.0000x reference)
//
#include <hip/hip_runtime.h>
#include <math.h>

#define NPIX 2304
#define NCH  512
#define NB   8
#define KNUM 230

typedef unsigned short u16;
typedef __attribute__((ext_vector_type(8))) short short8v;
typedef __attribute__((ext_vector_type(4))) float float4v;

__device__ __forceinline__ float bf2f(u16 u) {
    union { unsigned v; float f; } x; x.v = ((unsigned)u) << 16; return x.f;
}
__device__ __forceinline__ u16 f2bf(float f) {
    union { float f; unsigned v; } x; x.f = f;
    unsigned r = x.v + 0x7FFFu + ((x.v >> 16) & 1u);   // RNE
    return (u16)(r >> 16);
}

// ---------------- reductions ----------------
__device__ __forceinline__ float waveSum(float v) {
    #pragma unroll
    for (int o = 32; o > 0; o >>= 1) v += __shfl_down(v, o);
    return v;
}
__device__ __forceinline__ float blockSum256(float v, float* sc4) {
    v = waveSum(v);
    __syncthreads();
    if ((threadIdx.x & 63) == 0) sc4[threadIdx.x >> 6] = v;
    __syncthreads();
    return sc4[0] + sc4[1] + sc4[2] + sc4[3];
}
__device__ __forceinline__ float waveMaxF(float v) {
    #pragma unroll
    for (int o = 32; o > 0; o >>= 1) v = fmaxf(v, __shfl_down(v, o));
    return v;
}
__device__ __forceinline__ float blockMax256(float v, float* sc4) {
    v = waveMaxF(v);
    __syncthreads();
    if ((threadIdx.x & 63) == 0) sc4[threadIdx.x >> 6] = v;
    __syncthreads();
    return fmaxf(fmaxf(sc4[0], sc4[1]), fmaxf(sc4[2], sc4[3]));
}

// ---------------- async global->LDS 16B ----------------
__device__ __forceinline__ void gl_lds16(const u16* g, u16* l) {
    __builtin_amdgcn_global_load_lds(
        reinterpret_cast<const unsigned __attribute__((address_space(1)))*>(
            reinterpret_cast<uintptr_t>(g)),
        reinterpret_cast<unsigned __attribute__((address_space(3)))*>(
            reinterpret_cast<uintptr_t>(l)),
        16, 0, 0);
}

// ---------------- bf16 MFMA GEMM ----------------
// D[R, Cl] = alpha*scaleR[R]*sum_k A[R,k]*B[Cl,k] + biasR[R] + biasC[b,Cl] + biasRB[b,R]
// A, B row-major, k contiguous. Output stored out[b][Cl][R] (R contiguous).
// flags: 1 = relu, 2 = fp32 output (else bf16). B1: source for k >= 512 (concat).
__global__ __launch_bounds__(256, 3) void mfma_gemm(
    const u16* __restrict__ A, int ldA, long sA,
    const u16* __restrict__ B0, const u16* __restrict__ B1, int ldB, long sB,
    void* __restrict__ outp, int ldO, long sO,
    const float* __restrict__ scaleR, const float* __restrict__ biasR,
    const float* __restrict__ biasC, int ldbc,
    const float* __restrict__ biasRB, int ldrb,
    int K, float alpha, int flags)
{
    __shared__ u16 lA[128 * 64];
    __shared__ u16 lB[128 * 64];
    const int t  = threadIdx.x;
    const int w  = t >> 6, l = t & 63;
    const int wR = w >> 1, wC = w & 1;
    const int lg = l >> 4, lr = l & 15, l7 = l & 7;
    const int b   = blockIdx.z;
    const int Cl0 = blockIdx.x * 128;
    const int R0  = blockIdx.y * 128;
    const u16* Ab  = A + (size_t)b * sA;
    const u16* B0b = B0 + (size_t)b * sB;
    const u16* B1b = B1 ? B1 + (size_t)b * sB : nullptr;

    float4v acc[4][4];
    const float4v zero = {0.f, 0.f, 0.f, 0.f};
    #pragma unroll
    for (int i = 0; i < 4; ++i)
        #pragma unroll
        for (int j = 0; j < 4; ++j) acc[i][j] = zero;

    const int sr = t >> 3;     // staging row-in-issue (0..31)
    const int sp = t & 7;      // physical 16B chunk

    for (int k0 = 0; k0 < K; k0 += 64) {
        const u16* Bsrc = B0b; int kb = k0;
        if (B1b && k0 >= 512) { Bsrc = B1b; kb = k0 - 512; }
        #pragma unroll
        for (int i = 0; i < 4; ++i) {
            const int r  = i * 32 + sr;
            const int ca = sp ^ (r & 7);                  // pre-swizzled source chunk
            gl_lds16(Ab   + (size_t)(R0  + r) * ldA + (k0 + ca * 8), &lA[i * 2048 + t * 8]);
            gl_lds16(Bsrc + (size_t)(Cl0 + r) * ldB + (kb + ca * 8), &lB[i * 2048 + t * 8]);
        }
        __syncthreads();
        #pragma unroll
        for (int kk = 0; kk < 2; ++kk) {
            short8v af[4], bfv[4];
            const int p = (kk * 4 + lg) ^ l7;             // swizzled read chunk
            #pragma unroll
            for (int mt = 0; mt < 4; ++mt) {
                const int rA = wR * 64 + mt * 16 + lr;
                af[mt]  = *reinterpret_cast<const short8v*>(&lA[rA * 64 + p * 8]);
                const int rB = wC * 64 + mt * 16 + lr;
                bfv[mt] = *reinterpret_cast<const short8v*>(&lB[rB * 64 + p * 8]);
            }
            #pragma unroll
            for (int mt = 0; mt < 4; ++mt)
                #pragma unroll
                for (int nt = 0; nt < 4; ++nt)
                    acc[mt][nt] = __builtin_amdgcn_mfma_f32_16x16x32_bf16(
                        af[mt], bfv[nt], acc[mt][nt], 0, 0, 0);
        }
        __syncthreads();
    }

    const bool relu = (flags & 1), f32o = (flags & 2);
    #pragma unroll
    for (int nt = 0; nt < 4; ++nt) {
        const int Cl = Cl0 + wC * 64 + nt * 16 + lr;
        const float bc = biasC ? biasC[(size_t)b * ldbc + Cl] : 0.f;
        #pragma unroll
        for (int mt = 0; mt < 4; ++mt) {
            const int Rb = R0 + wR * 64 + mt * 16 + lg * 4;
            float4 scv = scaleR ? *reinterpret_cast<const float4*>(&scaleR[Rb])
                                : make_float4(1.f, 1.f, 1.f, 1.f);
            float4 bv  = biasR  ? *reinterpret_cast<const float4*>(&biasR[Rb])
                                : make_float4(0.f, 0.f, 0.f, 0.f);
            float4 rbv = biasRB ? *reinterpret_cast<const float4*>(&biasRB[(size_t)b * ldrb + Rb])
                                : make_float4(0.f, 0.f, 0.f, 0.f);
            float vals[4];
            #pragma unroll
            for (int j = 0; j < 4; ++j) {
                const float sc = alpha * ((&scv.x)[j]);
                float v = acc[mt][nt][j] * sc + (&bv.x)[j] + bc + (&rbv.x)[j];
                if (relu) v = fmaxf(v, 0.f);
                vals[j] = v;
            }
            if (f32o) {
                float* op = (float*)outp + (size_t)b * sO + (size_t)Cl * ldO + Rb;
                *reinterpret_cast<float4*>(op) = make_float4(vals[0], vals[1], vals[2], vals[3]);
            } else {
                ushort4 u;
                u.x = f2bf(vals[0]); u.y = f2bf(vals[1]);
                u.z = f2bf(vals[2]); u.w = f2bf(vals[3]);
                u16* op = (u16*)outp + (size_t)b * sO + (size_t)Cl * ldO + Rb;
                *reinterpret_cast<ushort4*>(op) = u;
            }
        }
    }
}

// ---------------- transpose+convert x + fused mask-logit partial dot ----------------
__global__ __launch_bounds__(256) void transpose_cvt_ml(
    const float* __restrict__ x, const float* __restrict__ cmw,
    u16* __restrict__ xb, float* __restrict__ logits)
{
    __shared__ float tile[64][65];
    const int t = threadIdx.x;
    const int n0 = blockIdx.x * 64, c0 = blockIdx.y * 64, b = blockIdx.z;
    const int tr = t >> 4, tc4 = (t & 15) * 4;
    #pragma unroll
    for (int i = 0; i < 4; ++i) {
        const int cc = tr + i * 16;
        float4 v = *reinterpret_cast<const float4*>(
            x + ((size_t)(b * NCH + c0 + cc)) * NPIX + n0 + tc4);
        tile[cc][tc4 + 0] = v.x; tile[cc][tc4 + 1] = v.y;
        tile[cc][tc4 + 2] = v.z; tile[cc][tc4 + 3] = v.w;
    }
    __syncthreads();
    #pragma unroll
    for (int i = 0; i < 4; ++i) {
        const int nn = tr + i * 16;
        ushort4 u;
        u.x = f2bf(tile[tc4 + 0][nn]); u.y = f2bf(tile[tc4 + 1][nn]);
        u.z = f2bf(tile[tc4 + 2][nn]); u.w = f2bf(tile[tc4 + 3][nn]);
        *reinterpret_cast<ushort4*>(xb + ((size_t)b * NPIX + n0 + nn) * NCH + c0 + tc4) = u;
    }
    const int nl = t >> 2, q = t & 3;
    float s = 0.f;
    #pragma unroll
    for (int k = 0; k < 16; ++k) {
        const int cc = q * 16 + k;
        s = fmaf(tile[cc][nl], cmw[c0 + cc], s);
    }
    s += __shfl_xor(s, 1);
    s += __shfl_xor(s, 2);
    if (q == 0) atomicAdd(&logits[(size_t)b * NPIX + n0 + nl], s);
}

// ---------------- w3T scaled: w3t[k][c] = lb_w3[c][k] * g3[c] * invs, bf16 ----------------
__global__ __launch_bounds__(256) void transpose_w3(
    const float* __restrict__ w3, const float* __restrict__ g3, u16* __restrict__ w3t)
{
    __shared__ float tile[64][65];
    const int t = threadIdx.x;
    const int k0 = blockIdx.x * 64, c0 = blockIdx.y * 64;
    const int tr = t >> 4, tc4 = (t & 15) * 4;
    #pragma unroll
    for (int i = 0; i < 4; ++i) {
        const int cc = tr + i * 16;
        const float s = g3[c0 + cc] * 0.99999500003749978f;
        float4 v = *reinterpret_cast<const float4*>(&w3[(size_t)(c0 + cc) * 512 + k0 + tc4]);
        tile[cc][tc4 + 0] = v.x * s; tile[cc][tc4 + 1] = v.y * s;
        tile[cc][tc4 + 2] = v.z * s; tile[cc][tc4 + 3] = v.w * s;
    }
    __syncthreads();
    #pragma unroll
    for (int i = 0; i < 4; ++i) {
        const int kk = tr + i * 16;
        ushort4 u;
        u.x = f2bf(tile[tc4 + 0][kk]); u.y = f2bf(tile[tc4 + 1][kk]);
        u.z = f2bf(tile[tc4 + 2][kk]); u.w = f2bf(tile[tc4 + 3][kk]);
        *reinterpret_cast<ushort4*>(&w3t[(size_t)(k0 + kk) * 512 + c0 + tc4]) = u;
    }
}

// ---------------- all weight conversions in one dispatch ----------------
__device__ __forceinline__ void cvt4(const float* s, u16* d, int i) {
    float4 v = reinterpret_cast<const float4*>(s)[i];
    ushort4 u; u.x = f2bf(v.x); u.y = f2bf(v.y); u.z = f2bf(v.z); u.w = f2bf(v.w);
    reinterpret_cast<ushort4*>(d)[i] = u;
}
__global__ __launch_bounds__(256) void prep_weights(
    const float* __restrict__ w1, const float* __restrict__ fu,
    const float* __restrict__ fin, const float* __restrict__ qw,
    const float* __restrict__ kw, const float* __restrict__ vw,
    const float* __restrict__ dww, const float* __restrict__ dwg,
    u16* __restrict__ w1b, u16* __restrict__ fuwb, u16* __restrict__ finwb,
    u16* __restrict__ qkvwb, float* __restrict__ wfold)
{
    const int i = blockIdx.x * 256 + threadIdx.x;
    if (i < 65536)            cvt4(w1, w1b, i);
    else if (i < 196608)      cvt4(fu, fuwb, i - 65536);
    else if (i < 327680)      cvt4(fin, finwb, i - 196608);
    else if (i < 344064)      cvt4(qw, qkvwb, i - 327680);
    else if (i < 360448)      cvt4(kw, qkvwb + 128 * 512, i - 344064);
    else if (i < 425984)      cvt4(vw, qkvwb + 256 * 512, i - 360448);
    else if (i < 425984 + 4608) {
        const int j = i - 425984;
        const int c = j / 9, tap = j % 9;
        wfold[tap * NCH + c] = dww[j] * dwg[c] * 0.99999500003749978f;
    }
}

// ---------------- depthwise 3x3 + BN + ReLU, [n][c] bf16 ----------------
__global__ __launch_bounds__(256) void dwconv_k(
    const u16* __restrict__ t1, const float* __restrict__ wf,
    const float* __restrict__ b2, u16* __restrict__ t2)
{
    const int idx = blockIdx.x * 256 + threadIdx.x;
    const int cq = idx & 127;
    const int n  = (idx >> 7) % NPIX;
    const int b  = (idx >> 7) / NPIX;
    const int c  = cq * 4;
    const int y = n / 48, x = n % 48;
    float s0 = 0.f, s1 = 0.f, s2 = 0.f, s3 = 0.f;
    #pragma unroll
    for (int dy = -1; dy <= 1; ++dy) {
        const int yy = y + dy;
        if (yy < 0 || yy >= 48) continue;
        #pragma unroll
        for (int dx = -1; dx <= 1; ++dx) {
            const int xx = x + dx;
            if (xx < 0 || xx >= 48) continue;
            ushort4 tv = *reinterpret_cast<const ushort4*>(
                &t1[((size_t)b * NPIX + yy * 48 + xx) * NCH + c]);
            float4 wv = *reinterpret_cast<const float4*>(
                &wf[((dy + 1) * 3 + dx + 1) * NCH + c]);
            s0 = fmaf(bf2f(tv.x), wv.x, s0); s1 = fmaf(bf2f(tv.y), wv.y, s1);
            s2 = fmaf(bf2f(tv.z), wv.z, s2); s3 = fmaf(bf2f(tv.w), wv.w, s3);
        }
    }
    float4 bb = *reinterpret_cast<const float4*>(&b2[c]);
    ushort4 o;
    o.x = f2bf(fmaxf(s0 + bb.x, 0.f)); o.y = f2bf(fmaxf(s1 + bb.y, 0.f));
    o.z = f2bf(fmaxf(s2 + bb.z, 0.f)); o.w = f2bf(fmaxf(s3 + bb.w, 0.f));
    *reinterpret_cast<ushort4*>(&t2[((size_t)b * NPIX + n) * NCH + c]) = o;
}

// ---------------- ContextBlock ----------------
__global__ __launch_bounds__(256) void softmax_mask(
    const float* __restrict__ logits, float* __restrict__ mask)
{
    __shared__ float sc[4];
    const int b = blockIdx.x, t = threadIdx.x;
    const float* lr = logits + (size_t)b * NPIX;
    float mx = -3.4e38f;
    for (int i = t; i < NPIX; i += 256) mx = fmaxf(mx, lr[i]);
    mx = blockMax256(mx, sc);
    float s = 0.f;
    for (int i = t; i < NPIX; i += 256) s += __expf(lr[i] - mx);
    s = blockSum256(s, sc);
    const float inv = 1.0f / s;
    for (int i = t; i < NPIX; i += 256) mask[(size_t)b * NPIX + i] = __expf(lr[i] - mx) * inv;
}

__global__ __launch_bounds__(512) void ctx_pool_k(
    const u16* __restrict__ xb, const float* __restrict__ mask, float* __restrict__ ctx)
{
    const int c = threadIdx.x, b = blockIdx.y;
    const int nn0 = blockIdx.x * 128;
    float s = 0.f;
    for (int n = nn0; n < nn0 + 128; ++n)
        s = fmaf(bf2f(xb[((size_t)b * NPIX + n) * NCH + c]), mask[(size_t)b * NPIX + n], s);
    atomicAdd(&ctx[b * NCH + c], s);
}

// ---------------- channel MLP: 3 stages, wave-per-dot parallelism ----------------
__global__ __launch_bounds__(256) void chan_h(
    const float* __restrict__ ctxv,
    const float* __restrict__ mw1, const float* __restrict__ mb1,
    const float* __restrict__ aw1, const float* __restrict__ ab1,
    float* __restrict__ hnb)
{
    const int w = threadIdx.x >> 6, l = threadIdx.x & 63;
    const int gid = blockIdx.x * 4 + w;          // 0..2047
    const int path = gid >> 10;
    const int rem  = gid & 1023;
    const int h = rem >> 3, b = rem & 7;
    const float* W1 = path ? aw1 : mw1;
    const float* B1 = path ? ab1 : mb1;
    const float4 wa = *reinterpret_cast<const float4*>(&W1[h * 512 + l * 8]);
    const float4 wb = *reinterpret_cast<const float4*>(&W1[h * 512 + l * 8 + 4]);
    const float4 ca = *reinterpret_cast<const float4*>(&ctxv[b * 512 + l * 8]);
    const float4 cb = *reinterpret_cast<const float4*>(&ctxv[b * 512 + l * 8 + 4]);
    float s = wa.x * ca.x + wa.y * ca.y + wa.z * ca.z + wa.w * ca.w
            + wb.x * cb.x + wb.y * cb.y + wb.z * cb.z + wb.w * cb.w;
    s = waveSum(s);
    if (l == 0) hnb[(path * 8 + b) * 128 + h] = s + B1[h];
}

__global__ __launch_bounds__(128) void chan_ln(
    const float* __restrict__ mlg, const float* __restrict__ mlb,
    const float* __restrict__ alg, const float* __restrict__ alb,
    float* __restrict__ hnb)
{
    __shared__ float sc[2];
    const int path = blockIdx.x, b = blockIdx.y, t = threadIdx.x;
    float* hp = hnb + (path * 8 + b) * 128;
    const float v = hp[t];
    float s1 = waveSum(v);
    if ((t & 63) == 0) sc[t >> 6] = s1;
    __syncthreads();
    const float mu = (sc[0] + sc[1]) * (1.0f / 128.0f);
    const float d = v - mu;
    float s2 = waveSum(d * d);
    __syncthreads();
    if ((t & 63) == 0) sc[t >> 6] = s2;
    __syncthreads();
    const float var = (sc[0] + sc[1]) * (1.0f / 128.0f);
    const float* LG = path ? alg : mlg;
    const float* LB = path ? alb : mlb;
    hp[t] = fmaxf(d / sqrtf(var + 1e-5f) * LG[t] + LB[t], 0.f);
}

__global__ __launch_bounds__(128) void chan_o(
    const float* __restrict__ hnb,
    const float* __restrict__ mw2, const float* __restrict__ mb2,
    const float* __restrict__ aw2, const float* __restrict__ ab2,
    float* __restrict__ mulo, float* __restrict__ addo)
{
    __shared__ float hs[128];
    const int oc = blockIdx.x, path = blockIdx.y, b = blockIdx.z;
    const int t = threadIdx.x;
    hs[t] = hnb[(path * 8 + b) * 128 + t];
    __syncthreads();
    const int o = oc * 128 + t;
    const float* W2 = path ? aw2 : mw2;
    float s = (path ? ab2 : mb2)[o];
    #pragma unroll
    for (int p = 0; p < 128; p += 4) {
        const float4 wv = *reinterpret_cast<const float4*>(&W2[o * 128 + p]);
        s += wv.x * hs[p] + wv.y * hs[p + 1] + wv.z * hs[p + 2] + wv.w * hs[p + 3];
    }
    if (path == 0) mulo[b * 512 + o] = 1.0f / (1.0f + __expf(-s));
    else           addo[b * 512 + o] = s;
}

// ---------------- per-batch glob weights ----------------
__global__ __launch_bounds__(256) void scale_wglob(
    const float* __restrict__ fuw, const float* __restrict__ mulv, u16* __restrict__ wf)
{
    const int idx = blockIdx.x * 256 + threadIdx.x;   // 8*512*128
    const int cq = idx & 127;
    const int o  = (idx >> 7) & 511;
    const int b  = idx >> 16;
    const int c  = cq * 4;
    float4 w = *reinterpret_cast<const float4*>(&fuw[(size_t)o * 1024 + 512 + c]);
    float4 m = *reinterpret_cast<const float4*>(&mulv[b * 512 + c]);
    ushort4 u;
    u.x = f2bf(w.x * m.x); u.y = f2bf(w.y * m.y);
    u.z = f2bf(w.z * m.z); u.w = f2bf(w.w * m.w);
    *reinterpret_cast<ushort4*>(&wf[(size_t)b * 524288 + (size_t)o * 1024 + 512 + c]) = u;
}

// fb[b][o] = fu_b[o] + sum_c fu_w[o,c]*b3[c] + sum_c fu_w[o,512+c]*add[b,c]
__global__ __launch_bounds__(256) void fuse_bias(
    const float* __restrict__ fuw, const float* __restrict__ fub,
    const float* __restrict__ b3, const float* __restrict__ addv, float* __restrict__ fb)
{
    const int o = blockIdx.x * 256 + threadIdx.x;     // grid.x = 2
    const int b = blockIdx.y;
    const float* wr = fuw + (size_t)o * 1024;
    float s = fub[o];
    for (int c = 0; c < 512; c += 4) {
        float4 w1 = *reinterpret_cast<const float4*>(&wr[c]);
        float4 bv = *reinterpret_cast<const float4*>(&b3[c]);
        float4 w2 = *reinterpret_cast<const float4*>(&wr[512 + c]);
        float4 av = *reinterpret_cast<const float4*>(&addv[b * 512 + c]);
        s += w1.x * bv.x + w1.y * bv.y + w1.z * bv.z + w1.w * bv.w
           + w2.x * av.x + w2.y * av.y + w2.z * av.z + w2.w * av.w;
    }
    fb[b * 512 + o] = s;
}

// ---------------- wave-per-row softmax + exact top-k on bf16 keys ----------------
// Counting split across pipes: 16 keys via ballot+s_bcnt (SALU), 20 keys via
// v_bcnt_u32_b32 on the ballot SGPRs (VALU) -- relieves the per-CU scalar unit.
__global__ __launch_bounds__(256) void softmax_topk_wave(
    const u16* __restrict__ p, float* __restrict__ mxo,
    float* __restrict__ invSo, float* __restrict__ softo)
{
    const int w = threadIdx.x >> 6, l = threadIdx.x & 63;
    const int r = blockIdx.x * 4 + w;
    const int bc = blockIdx.y;
    const u16* pr = p + ((size_t)bc * NPIX + r) * NPIX;
    const uint4* p16 = reinterpret_cast<const uint4*>(pr);
    uint4 q0 = p16[l], q1 = p16[64 + l], q2 = p16[128 + l], q3 = p16[192 + l];
    uint2 q4 = reinterpret_cast<const uint2*>(pr)[512 + l];
    unsigned uw[18] = {q0.x, q0.y, q0.z, q0.w, q1.x, q1.y, q1.z, q1.w,
                       q2.x, q2.y, q2.z, q2.w, q3.x, q3.y, q3.z, q3.w,
                       q4.x, q4.y};
    unsigned km[36];
    #pragma unroll
    for (int i = 0; i < 18; ++i) {
        const unsigned v = uw[i];
        const unsigned m = ((v >> 15) & 0x10001u) * 0x7FFFu + 0x80008000u;
        const unsigned s = v ^ m;           // two sortable keys packed
        km[2 * i]     = s & 0xFFFFu;
        km[2 * i + 1] = s >> 16;
    }
    unsigned kmax = km[0];
    #pragma unroll
    for (int i = 1; i < 36; ++i) kmax = max(kmax, km[i]);
    #pragma unroll
    for (int o = 32; o > 0; o >>= 1) kmax = max(kmax, (unsigned)__shfl_xor((int)kmax, o));
    const unsigned mxbits = (kmax & 0x8000u) ? (kmax ^ 0x8000u) : (kmax ^ 0xFFFFu);
    const float mx = bf2f((u16)mxbits);
    // MSB-first exact k-th search, split-pipe counting
    unsigned kt = 0u;
    for (int bit = 15; bit >= 0; --bit) {
        const unsigned cand = kt | (1u << bit);
        int cs = 0;
        unsigned cv0 = 0, cv1 = 0;
        #pragma unroll
        for (int i = 0; i < 36; ++i) {
            unsigned long long m = __ballot(km[i] >= cand);
            if (i < 16) {
                cs += (int)__popcll(m);
            } else if (i & 1) {
                asm("v_bcnt_u32_b32 %0, %1, %0" : "+v"(cv0) : "s"((unsigned)m));
                asm("v_bcnt_u32_b32 %0, %1, %0" : "+v"(cv0) : "s"((unsigned)(m >> 32)));
            } else {
                asm("v_bcnt_u32_b32 %0, %1, %0" : "+v"(cv1) : "s"((unsigned)m));
                asm("v_bcnt_u32_b32 %0, %1, %0" : "+v"(cv1) : "s"((unsigned)(m >> 32)));
            }
        }
        const int c = cs + (int)__builtin_amdgcn_readfirstlane((int)(cv0 + cv1));
        if (c >= KNUM) kt = cand;
    }
    const unsigned tbits = (kt & 0x8000u) ? (kt ^ 0x8000u) : (kt ^ 0xFFFFu);
    const float te = __expf(bf2f((u16)tbits) - mx);
    float S = 0.f, ss = 0.f;
    int as = 0;
    unsigned av0 = 0, av1 = 0;
    #pragma unroll
    for (int i = 0; i < 36; ++i) {
        const unsigned bb = (km[i] & 0x8000u) ? (km[i] ^ 0x8000u) : (km[i] ^ 0xFFFFu);
        const float e = __expf(bf2f((u16)bb) - mx);
        S += e;
        const bool gt = km[i] > kt;
        if (gt) ss += e;
        unsigned long long m = __ballot(gt);
        if (i < 16) {
            as += (int)__popcll(m);
        } else if (i & 1) {
            asm("v_bcnt_u32_b32 %0, %1, %0" : "+v"(av0) : "s"((unsigned)m));
            asm("v_bcnt_u32_b32 %0, %1, %0" : "+v"(av0) : "s"((unsigned)(m >> 32)));
        } else {
            asm("v_bcnt_u32_b32 %0, %1, %0" : "+v"(av1) : "s"((unsigned)m));
            asm("v_bcnt_u32_b32 %0, %1, %0" : "+v"(av1) : "s"((unsigned)(m >> 32)));
        }
    }
    const int a = as + (int)__builtin_amdgcn_readfirstlane((int)(av0 + av1));
    #pragma unroll
    for (int o = 32; o > 0; o >>= 1) { S += __shfl_xor(S, o); ss += __shfl_xor(ss, o); }
    if (l == 0) {
        const size_t gi = (size_t)bc * NPIX + r;
        mxo[gi] = mx; invSo[gi] = 1.0f / S;
        softo[gi] = (ss + (float)(KNUM - a) * te) / (S * (float)KNUM);
    }
}

// colsum[b][j] = sum_i exp(p[i][j]-mx[i]) * invS[i]; 4 cols/thread via ushort4.
__global__ __launch_bounds__(64) void colsum_k(
    const u16* __restrict__ p, const float* __restrict__ mxo,
    const float* __restrict__ invSo, float* __restrict__ colsum)
{
    const int chunk = blockIdx.x * 64 + threadIdx.x;   // 0..575 -> cols 4c..4c+3
    const int ic0 = blockIdx.y * 36;
    const int bc = blockIdx.z;
    const float* mxr = mxo + (size_t)bc * NPIX;
    const float* isr = invSo + (size_t)bc * NPIX;
    const u16* pb = p + (size_t)bc * NPIX * NPIX + chunk * 4;
    float s0 = 0.f, s1 = 0.f, s2 = 0.f, s3 = 0.f;
    #pragma unroll 4
    for (int i = ic0; i < ic0 + 36; ++i) {
        ushort4 v = *reinterpret_cast<const ushort4*>(pb + (size_t)i * NPIX);
        const float m = mxr[i], is = isr[i];
        s0 = fmaf(__expf(bf2f(v.x) - m), is, s0);
        s1 = fmaf(__expf(bf2f(v.y) - m), is, s1);
        s2 = fmaf(__expf(bf2f(v.z) - m), is, s2);
        s3 = fmaf(__expf(bf2f(v.w) - m), is, s3);
    }
    float* cb = colsum + (size_t)bc * NPIX + chunk * 4;
    atomicAdd(cb + 0, s0); atomicAdd(cb + 1, s1);
    atomicAdd(cb + 2, s2); atomicAdd(cb + 3, s3);
}

__global__ __launch_bounds__(512) void ctx2_pool_k(
    const u16* __restrict__ qkv, const float* __restrict__ colsum,
    const float* __restrict__ soft, float* __restrict__ ctx2)
{
    const int c = threadIdx.x, b = blockIdx.y;
    const int nn0 = blockIdx.x * 128;
    float s = 0.f;
    for (int n = nn0; n < nn0 + 128; ++n) {
        const float wgt = colsum[(size_t)b * NPIX + n] * soft[(size_t)b * NPIX + n];
        s = fmaf(bf2f(qkv[((size_t)b * NPIX + n) * 768 + 256 + c]), wgt, s);
    }
    atomicAdd(&ctx2[b * NCH + c], s * (1.0f / (float)NPIX));
}

__global__ __launch_bounds__(256) void compute_z(
    const float* __restrict__ finw, const float* __restrict__ ctx2, float* __restrict__ z)
{
    const int o = blockIdx.x * 256 + threadIdx.x;
    const int b = blockIdx.y;
    const float* c2 = ctx2 + b * NCH;
    const float* wr = finw + (size_t)o * 1024 + 512;
    float s = 0.f;
    for (int c = 0; c < NCH; ++c) s = fmaf(wr[c], c2[c], s);
    z[b * NCH + o] = s;
}

// ---------------- host launcher ----------------
extern "C" void kernel_launch(void* const* d_in, const int* in_sizes, int n_in,
                              void* d_out, int out_size, void* d_ws, size_t ws_size,
                              hipStream_t stream)
{
    (void)in_sizes; (void)n_in; (void)out_size; (void)ws_size;
    const float* x      = (const float*)d_in[0];
    const float* lb_w1  = (const float*)d_in[1];
    const float* lb_g1  = (const float*)d_in[2];
    const float* lb_b1  = (const float*)d_in[3];
    const float* lb_w2  = (const float*)d_in[4];
    const float* lb_g2  = (const float*)d_in[5];
    const float* lb_b2  = (const float*)d_in[6];
    const float* lb_w3  = (const float*)d_in[7];
    const float* lb_g3  = (const float*)d_in[8];
    const float* lb_b3  = (const float*)d_in[9];
    const float* cm_w   = (const float*)d_in[10];
    // cm_b (d_in[11]) unused: softmax is shift-invariant to a scalar logit bias
    const float* ca_w1  = (const float*)d_in[12];
    const float* ca_b1  = (const float*)d_in[13];
    const float* ca_lg  = (const float*)d_in[14];
    const float* ca_lb  = (const float*)d_in[15];
    const float* ca_w2  = (const float*)d_in[16];
    const float* ca_b2  = (const float*)d_in[17];
    const float* cmu_w1 = (const float*)d_in[18];
    const float* cmu_b1 = (const float*)d_in[19];
    const float* cmu_lg = (const float*)d_in[20];
    const float* cmu_lb = (const float*)d_in[21];
    const float* cmu_w2 = (const float*)d_in[22];
    const float* cmu_b2 = (const float*)d_in[23];
    const float* fu_w   = (const float*)d_in[24];
    const float* fu_b   = (const float*)d_in[25];
    // 26..37 dead (region == 1 identically)
    const float* q_w    = (const float*)d_in[38];
    const float* k_w    = (const float*)d_in[39];
    const float* v_w    = (const float*)d_in[40];
    const float* fin_w  = (const float*)d_in[41];

    char* W = (char*)d_ws;
    const size_t SZ_ACT = (size_t)NB * NPIX * NCH * 2;     // 18,874,368 B
    u16* xb   = (u16*)(W);
    u16* bufA = (u16*)(W + SZ_ACT);                        // t1
    u16* bufB = (u16*)(W + 2 * SZ_ACT);                    // t2
    u16* gx   = (u16*)(W + 3 * SZ_ACT);
    u16* qkv  = (u16*)(W + 4 * SZ_ACT);                    // [b][n][768]
    u16* wfused = qkv;         // [8][512][1024] bf16, dead before qkv is written
    u16* pbuf = (u16*)(W + 4 * SZ_ACT + (size_t)NB * NPIX * 768 * 2);   // [8][N][N] bf16
    char* SM = (char*)(pbuf + (size_t)NB * NPIX * NPIX);
    float* logits = (float*)SM; SM += (size_t)NB * NPIX * 4;  // zero region start
    float* colsum = (float*)SM; SM += (size_t)NB * NPIX * 4;
    float* ctxb   = (float*)SM; SM += (size_t)NB * NCH * 4;
    float* ctx2b  = (float*)SM; SM += (size_t)NB * NCH * 4;   // zero region end
    float* maskb  = (float*)SM; SM += (size_t)NB * NPIX * 4;
    float* mxb    = (float*)SM; SM += (size_t)NB * NPIX * 4;
    float* invSb  = (float*)SM; SM += (size_t)NB * NPIX * 4;
    float* softb  = (float*)SM; SM += (size_t)NB * NPIX * 4;
    float* mulb   = (float*)SM; SM += (size_t)NB * NCH * 4;
    float* addb   = (float*)SM; SM += (size_t)NB * NCH * 4;
    float* zbuf   = (float*)SM; SM += (size_t)NB * NCH * 4;
    float* fbias  = (float*)SM; SM += (size_t)NB * NCH * 4;
    float* hnb    = (float*)SM; SM += (size_t)2 * NB * 128 * 4;
    float* wfold  = (float*)SM; SM += (size_t)9 * NCH * 4;
    u16* w1b   = (u16*)SM; SM += (size_t)512 * 512 * 2;
    u16* fuwb  = (u16*)SM; SM += (size_t)512 * 1024 * 2;
    u16* finwb = (u16*)SM; SM += (size_t)512 * 1024 * 2;
    u16* qkvwb = (u16*)SM; SM += (size_t)768 * 512 * 2;
    u16* w3t   = (u16*)SM; SM += (size_t)512 * 512 * 2;

    const float invs  = 0.99999500003749978f;   // 1/sqrt(1+1e-5)
    const float rs128 = 0.08838834764831845f;   // 1/sqrt(128)
    const long SACT = (long)NPIX * NCH;

    // zero logits/colsum/ctx/ctx2 first (logits accumulated by atomics)
    hipMemsetAsync(logits, 0,
        ((size_t)2 * NB * NPIX + (size_t)2 * NB * NCH) * 4, stream);
    // weight conversions in one dispatch
    prep_weights<<<1683, 256, 0, stream>>>(lb_w1, fu_w, fin_w, q_w, k_w, v_w,
        lb_w2, lb_g2, w1b, fuwb, finwb, qkvwb, wfold);
    transpose_cvt_ml<<<dim3(36, 8, 8), 256, 0, stream>>>(x, cm_w, xb, logits);
    transpose_w3<<<dim3(8, 8), 256, 0, stream>>>(lb_w3, lb_g3, w3t);

    // W'' = (fu_local . diag(g3*invs)) @ w3  -> wfused[:, :512] (8 replicas)
    mfma_gemm<<<dim3(4, 4, 8), 256, 0, stream>>>(w3t, 512, 0, fuwb, nullptr, 1024, 0,
        wfused, 1024, 524288, nullptr, nullptr, nullptr, 0, nullptr, 0, 512, 1.0f, 0);

    // local branch start: t1 = relu(bn(W1 @ x)); t2 = relu(bn(dw3x3(t1)))
    mfma_gemm<<<dim3(18, 4, 8), 256, 0, stream>>>(w1b, 512, 0, xb, nullptr, 512, SACT,
        bufA, 512, SACT, lb_g1, lb_b1, nullptr, 0, nullptr, 0, 512, invs, 1);
    dwconv_k<<<9216, 256, 0, stream>>>(bufA, wfold, lb_b2, bufB);
    // ContextBlock
    softmax_mask<<<8, 256, 0, stream>>>(logits, maskb);
    ctx_pool_k<<<dim3(18, 8), 512, 0, stream>>>(xb, maskb, ctxb);
    chan_h<<<512, 256, 0, stream>>>(ctxb, cmu_w1, cmu_b1, ca_w1, ca_b1, hnb);
    chan_ln<<<dim3(2, 8), 128, 0, stream>>>(cmu_lg, cmu_lb, ca_lg, ca_lb, hnb);
    chan_o<<<dim3(4, 2, 8), 128, 0, stream>>>(hnb, cmu_w2, cmu_b2, ca_w2, ca_b2, mulb, addb);
    // per-batch glob weights + fused bias
    scale_wglob<<<2048, 256, 0, stream>>>(fu_w, mulb, wfused);
    fuse_bias<<<dim3(2, 8), 256, 0, stream>>>(fu_w, fu_b, lb_b3, addb, fbias);
    // fused gx GEMM: gx = W''@t2 + (fu_glob.mul_b)@x + fbias
    mfma_gemm<<<dim3(18, 4, 8), 256, 0, stream>>>(wfused, 1024, 524288, bufB, xb, 512, SACT,
        gx, 512, SACT, nullptr, nullptr, nullptr, 0, fbias, 512, 1024, 1.0f, 0);
    // q|k|v stacked projection (overwrites wfused region - wfused is dead)
    mfma_gemm<<<dim3(18, 6, 8), 256, 0, stream>>>(qkvwb, 512, 0, gx, nullptr, 512, SACT,
        qkv, 768, (long)NPIX * 768, nullptr, nullptr, nullptr, 0, nullptr, 0, 512, 1.0f, 0);
    // attention: single 8-batch pass
    mfma_gemm<<<dim3(18, 18, 8), 256, 0, stream>>>(qkv + 128, 768, (long)NPIX * 768,
        qkv, nullptr, 768, (long)NPIX * 768,
        pbuf, NPIX, (long)NPIX * NPIX, nullptr, nullptr, nullptr, 0, nullptr, 0,
        128, rs128, 0);
    softmax_topk_wave<<<dim3(576, 8), 256, 0, stream>>>(pbuf, mxb, invSb, softb);
    colsum_k<<<dim3(9, 64, 8), 64, 0, stream>>>(pbuf, mxb, invSb, colsum);
    // epilogue path
    ctx2_pool_k<<<dim3(18, 8), 512, 0, stream>>>(qkv, colsum, softb, ctx2b);
    compute_z<<<dim3(2, 8), 256, 0, stream>>>(fin_w, ctx2b, zbuf);
    mfma_gemm<<<dim3(4, 18, 8), 256, 0, stream>>>(gx, 512, SACT, finwb, nullptr, 1024, 0,
        d_out, NPIX, (long)NCH * NPIX, nullptr, nullptr, zbuf, 512, nullptr, 0,
        512, 1.0f, 2);
}

// Round 11
// 389.289 us; speedup vs baseline: 1.0407x; 1.0407x over previous
//
#include <hip/hip_runtime.h>
#include <math.h>

#define NPIX 2304
#define NCH  512
#define NB   8
#define KNUM 230

typedef unsigned short u16;
typedef __attribute__((ext_vector_type(8))) short short8v;
typedef __attribute__((ext_vector_type(4))) float float4v;

__device__ __forceinline__ float bf2f(u16 u) {
    union { unsigned v; float f; } x; x.v = ((unsigned)u) << 16; return x.f;
}
__device__ __forceinline__ u16 f2bf(float f) {
    union { float f; unsigned v; } x; x.f = f;
    unsigned r = x.v + 0x7FFFu + ((x.v >> 16) & 1u);   // RNE
    return (u16)(r >> 16);
}

// ---------------- reductions ----------------
__device__ __forceinline__ float waveSum(float v) {
    #pragma unroll
    for (int o = 32; o > 0; o >>= 1) v += __shfl_down(v, o);
    return v;
}
__device__ __forceinline__ float blockSum256(float v, float* sc4) {
    v = waveSum(v);
    __syncthreads();
    if ((threadIdx.x & 63) == 0) sc4[threadIdx.x >> 6] = v;
    __syncthreads();
    return sc4[0] + sc4[1] + sc4[2] + sc4[3];
}
__device__ __forceinline__ float waveMaxF(float v) {
    #pragma unroll
    for (int o = 32; o > 0; o >>= 1) v = fmaxf(v, __shfl_down(v, o));
    return v;
}
__device__ __forceinline__ float blockMax256(float v, float* sc4) {
    v = waveMaxF(v);
    __syncthreads();
    if ((threadIdx.x & 63) == 0) sc4[threadIdx.x >> 6] = v;
    __syncthreads();
    return fmaxf(fmaxf(sc4[0], sc4[1]), fmaxf(sc4[2], sc4[3]));
}

// ---------------- async global->LDS 16B ----------------
__device__ __forceinline__ void gl_lds16(const u16* g, u16* l) {
    __builtin_amdgcn_global_load_lds(
        reinterpret_cast<const unsigned __attribute__((address_space(1)))*>(
            reinterpret_cast<uintptr_t>(g)),
        reinterpret_cast<unsigned __attribute__((address_space(3)))*>(
            reinterpret_cast<uintptr_t>(l)),
        16, 0, 0);
}

// ---------------- bf16 MFMA GEMM ----------------
// D[R, Cl] = alpha*scaleR[R]*sum_k A[R,k]*B[Cl,k] + biasR[R] + biasC[b,Cl] + biasRB[b,R]
// A, B row-major, k contiguous. Output stored out[b][Cl][R] (R contiguous).
// flags: 1 = relu, 2 = fp32 output (else bf16). B1: source for k >= 512 (concat).
__global__ __launch_bounds__(256, 3) void mfma_gemm(
    const u16* __restrict__ A, int ldA, long sA,
    const u16* __restrict__ B0, const u16* __restrict__ B1, int ldB, long sB,
    void* __restrict__ outp, int ldO, long sO,
    const float* __restrict__ scaleR, const float* __restrict__ biasR,
    const float* __restrict__ biasC, int ldbc,
    const float* __restrict__ biasRB, int ldrb,
    int K, float alpha, int flags)
{
    __shared__ u16 lA[128 * 64];
    __shared__ u16 lB[128 * 64];
    const int t  = threadIdx.x;
    const int w  = t >> 6, l = t & 63;
    const int wR = w >> 1, wC = w & 1;
    const int lg = l >> 4, lr = l & 15, l7 = l & 7;
    const int b   = blockIdx.z;
    const int Cl0 = blockIdx.x * 128;
    const int R0  = blockIdx.y * 128;
    const u16* Ab  = A + (size_t)b * sA;
    const u16* B0b = B0 + (size_t)b * sB;
    const u16* B1b = B1 ? B1 + (size_t)b * sB : nullptr;

    float4v acc[4][4];
    const float4v zero = {0.f, 0.f, 0.f, 0.f};
    #pragma unroll
    for (int i = 0; i < 4; ++i)
        #pragma unroll
        for (int j = 0; j < 4; ++j) acc[i][j] = zero;

    const int sr = t >> 3;     // staging row-in-issue (0..31)
    const int sp = t & 7;      // physical 16B chunk

    for (int k0 = 0; k0 < K; k0 += 64) {
        const u16* Bsrc = B0b; int kb = k0;
        if (B1b && k0 >= 512) { Bsrc = B1b; kb = k0 - 512; }
        #pragma unroll
        for (int i = 0; i < 4; ++i) {
            const int r  = i * 32 + sr;
            const int ca = sp ^ (r & 7);                  // pre-swizzled source chunk
            gl_lds16(Ab   + (size_t)(R0  + r) * ldA + (k0 + ca * 8), &lA[i * 2048 + t * 8]);
            gl_lds16(Bsrc + (size_t)(Cl0 + r) * ldB + (kb + ca * 8), &lB[i * 2048 + t * 8]);
        }
        __syncthreads();
        #pragma unroll
        for (int kk = 0; kk < 2; ++kk) {
            short8v af[4], bfv[4];
            const int p = (kk * 4 + lg) ^ l7;             // swizzled read chunk
            #pragma unroll
            for (int mt = 0; mt < 4; ++mt) {
                const int rA = wR * 64 + mt * 16 + lr;
                af[mt]  = *reinterpret_cast<const short8v*>(&lA[rA * 64 + p * 8]);
                const int rB = wC * 64 + mt * 16 + lr;
                bfv[mt] = *reinterpret_cast<const short8v*>(&lB[rB * 64 + p * 8]);
            }
            #pragma unroll
            for (int mt = 0; mt < 4; ++mt)
                #pragma unroll
                for (int nt = 0; nt < 4; ++nt)
                    acc[mt][nt] = __builtin_amdgcn_mfma_f32_16x16x32_bf16(
                        af[mt], bfv[nt], acc[mt][nt], 0, 0, 0);
        }
        __syncthreads();
    }

    const bool relu = (flags & 1), f32o = (flags & 2);
    #pragma unroll
    for (int nt = 0; nt < 4; ++nt) {
        const int Cl = Cl0 + wC * 64 + nt * 16 + lr;
        const float bc = biasC ? biasC[(size_t)b * ldbc + Cl] : 0.f;
        #pragma unroll
        for (int mt = 0; mt < 4; ++mt) {
            const int Rb = R0 + wR * 64 + mt * 16 + lg * 4;
            float4 scv = scaleR ? *reinterpret_cast<const float4*>(&scaleR[Rb])
                                : make_float4(1.f, 1.f, 1.f, 1.f);
            float4 bv  = biasR  ? *reinterpret_cast<const float4*>(&biasR[Rb])
                                : make_float4(0.f, 0.f, 0.f, 0.f);
            float4 rbv = biasRB ? *reinterpret_cast<const float4*>(&biasRB[(size_t)b * ldrb + Rb])
                                : make_float4(0.f, 0.f, 0.f, 0.f);
            float vals[4];
            #pragma unroll
            for (int j = 0; j < 4; ++j) {
                const float sc = alpha * ((&scv.x)[j]);
                float v = acc[mt][nt][j] * sc + (&bv.x)[j] + bc + (&rbv.x)[j];
                if (relu) v = fmaxf(v, 0.f);
                vals[j] = v;
            }
            if (f32o) {
                float* op = (float*)outp + (size_t)b * sO + (size_t)Cl * ldO + Rb;
                *reinterpret_cast<float4*>(op) = make_float4(vals[0], vals[1], vals[2], vals[3]);
            } else {
                ushort4 u;
                u.x = f2bf(vals[0]); u.y = f2bf(vals[1]);
                u.z = f2bf(vals[2]); u.w = f2bf(vals[3]);
                u16* op = (u16*)outp + (size_t)b * sO + (size_t)Cl * ldO + Rb;
                *reinterpret_cast<ushort4*>(op) = u;
            }
        }
    }
}

// ---------------- transpose+convert x + fused mask-logit partial dot ----------------
__global__ __launch_bounds__(256) void transpose_cvt_ml(
    const float* __restrict__ x, const float* __restrict__ cmw,
    u16* __restrict__ xb, float* __restrict__ logits)
{
    __shared__ float tile[64][65];
    const int t = threadIdx.x;
    const int n0 = blockIdx.x * 64, c0 = blockIdx.y * 64, b = blockIdx.z;
    const int tr = t >> 4, tc4 = (t & 15) * 4;
    #pragma unroll
    for (int i = 0; i < 4; ++i) {
        const int cc = tr + i * 16;
        float4 v = *reinterpret_cast<const float4*>(
            x + ((size_t)(b * NCH + c0 + cc)) * NPIX + n0 + tc4);
        tile[cc][tc4 + 0] = v.x; tile[cc][tc4 + 1] = v.y;
        tile[cc][tc4 + 2] = v.z; tile[cc][tc4 + 3] = v.w;
    }
    __syncthreads();
    #pragma unroll
    for (int i = 0; i < 4; ++i) {
        const int nn = tr + i * 16;
        ushort4 u;
        u.x = f2bf(tile[tc4 + 0][nn]); u.y = f2bf(tile[tc4 + 1][nn]);
        u.z = f2bf(tile[tc4 + 2][nn]); u.w = f2bf(tile[tc4 + 3][nn]);
        *reinterpret_cast<ushort4*>(xb + ((size_t)b * NPIX + n0 + nn) * NCH + c0 + tc4) = u;
    }
    const int nl = t >> 2, q = t & 3;
    float s = 0.f;
    #pragma unroll
    for (int k = 0; k < 16; ++k) {
        const int cc = q * 16 + k;
        s = fmaf(tile[cc][nl], cmw[c0 + cc], s);
    }
    s += __shfl_xor(s, 1);
    s += __shfl_xor(s, 2);
    if (q == 0) atomicAdd(&logits[(size_t)b * NPIX + n0 + nl], s);
}

// ---------------- w3T scaled: w3t[k][c] = lb_w3[c][k] * g3[c] * invs, bf16 ----------------
__global__ __launch_bounds__(256) void transpose_w3(
    const float* __restrict__ w3, const float* __restrict__ g3, u16* __restrict__ w3t)
{
    __shared__ float tile[64][65];
    const int t = threadIdx.x;
    const int k0 = blockIdx.x * 64, c0 = blockIdx.y * 64;
    const int tr = t >> 4, tc4 = (t & 15) * 4;
    #pragma unroll
    for (int i = 0; i < 4; ++i) {
        const int cc = tr + i * 16;
        const float s = g3[c0 + cc] * 0.99999500003749978f;
        float4 v = *reinterpret_cast<const float4*>(&w3[(size_t)(c0 + cc) * 512 + k0 + tc4]);
        tile[cc][tc4 + 0] = v.x * s; tile[cc][tc4 + 1] = v.y * s;
        tile[cc][tc4 + 2] = v.z * s; tile[cc][tc4 + 3] = v.w * s;
    }
    __syncthreads();
    #pragma unroll
    for (int i = 0; i < 4; ++i) {
        const int kk = tr + i * 16;
        ushort4 u;
        u.x = f2bf(tile[tc4 + 0][kk]); u.y = f2bf(tile[tc4 + 1][kk]);
        u.z = f2bf(tile[tc4 + 2][kk]); u.w = f2bf(tile[tc4 + 3][kk]);
        *reinterpret_cast<ushort4*>(&w3t[(size_t)(k0 + kk) * 512 + c0 + tc4]) = u;
    }
}

// ---------------- all weight conversions in one dispatch ----------------
__device__ __forceinline__ void cvt4(const float* s, u16* d, int i) {
    float4 v = reinterpret_cast<const float4*>(s)[i];
    ushort4 u; u.x = f2bf(v.x); u.y = f2bf(v.y); u.z = f2bf(v.z); u.w = f2bf(v.w);
    reinterpret_cast<ushort4*>(d)[i] = u;
}
__global__ __launch_bounds__(256) void prep_weights(
    const float* __restrict__ w1, const float* __restrict__ fu,
    const float* __restrict__ fin, const float* __restrict__ qw,
    const float* __restrict__ kw, const float* __restrict__ vw,
    const float* __restrict__ dww, const float* __restrict__ dwg,
    u16* __restrict__ w1b, u16* __restrict__ fuwb, u16* __restrict__ finwb,
    u16* __restrict__ qkvwb, float* __restrict__ wfold)
{
    const int i = blockIdx.x * 256 + threadIdx.x;
    if (i < 65536)            cvt4(w1, w1b, i);
    else if (i < 196608)      cvt4(fu, fuwb, i - 65536);
    else if (i < 327680)      cvt4(fin, finwb, i - 196608);
    else if (i < 344064)      cvt4(qw, qkvwb, i - 327680);
    else if (i < 360448)      cvt4(kw, qkvwb + 128 * 512, i - 344064);
    else if (i < 425984)      cvt4(vw, qkvwb + 256 * 512, i - 360448);
    else if (i < 425984 + 4608) {
        const int j = i - 425984;
        const int c = j / 9, tap = j % 9;
        wfold[tap * NCH + c] = dww[j] * dwg[c] * 0.99999500003749978f;
    }
}

// ---------------- depthwise 3x3 + BN + ReLU, [n][c] bf16 ----------------
__global__ __launch_bounds__(256) void dwconv_k(
    const u16* __restrict__ t1, const float* __restrict__ wf,
    const float* __restrict__ b2, u16* __restrict__ t2)
{
    const int idx = blockIdx.x * 256 + threadIdx.x;
    const int cq = idx & 127;
    const int n  = (idx >> 7) % NPIX;
    const int b  = (idx >> 7) / NPIX;
    const int c  = cq * 4;
    const int y = n / 48, x = n % 48;
    float s0 = 0.f, s1 = 0.f, s2 = 0.f, s3 = 0.f;
    #pragma unroll
    for (int dy = -1; dy <= 1; ++dy) {
        const int yy = y + dy;
        if (yy < 0 || yy >= 48) continue;
        #pragma unroll
        for (int dx = -1; dx <= 1; ++dx) {
            const int xx = x + dx;
            if (xx < 0 || xx >= 48) continue;
            ushort4 tv = *reinterpret_cast<const ushort4*>(
                &t1[((size_t)b * NPIX + yy * 48 + xx) * NCH + c]);
            float4 wv = *reinterpret_cast<const float4*>(
                &wf[((dy + 1) * 3 + dx + 1) * NCH + c]);
            s0 = fmaf(bf2f(tv.x), wv.x, s0); s1 = fmaf(bf2f(tv.y), wv.y, s1);
            s2 = fmaf(bf2f(tv.z), wv.z, s2); s3 = fmaf(bf2f(tv.w), wv.w, s3);
        }
    }
    float4 bb = *reinterpret_cast<const float4*>(&b2[c]);
    ushort4 o;
    o.x = f2bf(fmaxf(s0 + bb.x, 0.f)); o.y = f2bf(fmaxf(s1 + bb.y, 0.f));
    o.z = f2bf(fmaxf(s2 + bb.z, 0.f)); o.w = f2bf(fmaxf(s3 + bb.w, 0.f));
    *reinterpret_cast<ushort4*>(&t2[((size_t)b * NPIX + n) * NCH + c]) = o;
}

// ---------------- ContextBlock ----------------
__global__ __launch_bounds__(256) void softmax_mask(
    const float* __restrict__ logits, float* __restrict__ mask)
{
    __shared__ float sc[4];
    const int b = blockIdx.x, t = threadIdx.x;
    const float* lr = logits + (size_t)b * NPIX;
    float mx = -3.4e38f;
    for (int i = t; i < NPIX; i += 256) mx = fmaxf(mx, lr[i]);
    mx = blockMax256(mx, sc);
    float s = 0.f;
    for (int i = t; i < NPIX; i += 256) s += __expf(lr[i] - mx);
    s = blockSum256(s, sc);
    const float inv = 1.0f / s;
    for (int i = t; i < NPIX; i += 256) mask[(size_t)b * NPIX + i] = __expf(lr[i] - mx) * inv;
}

__global__ __launch_bounds__(512) void ctx_pool_k(
    const u16* __restrict__ xb, const float* __restrict__ mask, float* __restrict__ ctx)
{
    const int c = threadIdx.x, b = blockIdx.y;
    const int nn0 = blockIdx.x * 128;
    float s = 0.f;
    for (int n = nn0; n < nn0 + 128; ++n)
        s = fmaf(bf2f(xb[((size_t)b * NPIX + n) * NCH + c]), mask[(size_t)b * NPIX + n], s);
    atomicAdd(&ctx[b * NCH + c], s);
}

// ---------------- channel MLP: 3 stages, wave-per-dot parallelism ----------------
__global__ __launch_bounds__(256) void chan_h(
    const float* __restrict__ ctxv,
    const float* __restrict__ mw1, const float* __restrict__ mb1,
    const float* __restrict__ aw1, const float* __restrict__ ab1,
    float* __restrict__ hnb)
{
    const int w = threadIdx.x >> 6, l = threadIdx.x & 63;
    const int gid = blockIdx.x * 4 + w;          // 0..2047
    const int path = gid >> 10;
    const int rem  = gid & 1023;
    const int h = rem >> 3, b = rem & 7;
    const float* W1 = path ? aw1 : mw1;
    const float* B1 = path ? ab1 : mb1;
    const float4 wa = *reinterpret_cast<const float4*>(&W1[h * 512 + l * 8]);
    const float4 wb = *reinterpret_cast<const float4*>(&W1[h * 512 + l * 8 + 4]);
    const float4 ca = *reinterpret_cast<const float4*>(&ctxv[b * 512 + l * 8]);
    const float4 cb = *reinterpret_cast<const float4*>(&ctxv[b * 512 + l * 8 + 4]);
    float s = wa.x * ca.x + wa.y * ca.y + wa.z * ca.z + wa.w * ca.w
            + wb.x * cb.x + wb.y * cb.y + wb.z * cb.z + wb.w * cb.w;
    s = waveSum(s);
    if (l == 0) hnb[(path * 8 + b) * 128 + h] = s + B1[h];
}

__global__ __launch_bounds__(128) void chan_ln(
    const float* __restrict__ mlg, const float* __restrict__ mlb,
    const float* __restrict__ alg, const float* __restrict__ alb,
    float* __restrict__ hnb)
{
    __shared__ float sc[2];
    const int path = blockIdx.x, b = blockIdx.y, t = threadIdx.x;
    float* hp = hnb + (path * 8 + b) * 128;
    const float v = hp[t];
    float s1 = waveSum(v);
    if ((t & 63) == 0) sc[t >> 6] = s1;
    __syncthreads();
    const float mu = (sc[0] + sc[1]) * (1.0f / 128.0f);
    const float d = v - mu;
    float s2 = waveSum(d * d);
    __syncthreads();
    if ((t & 63) == 0) sc[t >> 6] = s2;
    __syncthreads();
    const float var = (sc[0] + sc[1]) * (1.0f / 128.0f);
    const float* LG = path ? alg : mlg;
    const float* LB = path ? alb : mlb;
    hp[t] = fmaxf(d / sqrtf(var + 1e-5f) * LG[t] + LB[t], 0.f);
}

__global__ __launch_bounds__(128) void chan_o(
    const float* __restrict__ hnb,
    const float* __restrict__ mw2, const float* __restrict__ mb2,
    const float* __restrict__ aw2, const float* __restrict__ ab2,
    float* __restrict__ mulo, float* __restrict__ addo)
{
    __shared__ float hs[128];
    const int oc = blockIdx.x, path = blockIdx.y, b = blockIdx.z;
    const int t = threadIdx.x;
    hs[t] = hnb[(path * 8 + b) * 128 + t];
    __syncthreads();
    const int o = oc * 128 + t;
    const float* W2 = path ? aw2 : mw2;
    float s = (path ? ab2 : mb2)[o];
    #pragma unroll
    for (int p = 0; p < 128; p += 4) {
        const float4 wv = *reinterpret_cast<const float4*>(&W2[o * 128 + p]);
        s += wv.x * hs[p] + wv.y * hs[p + 1] + wv.z * hs[p + 2] + wv.w * hs[p + 3];
    }
    if (path == 0) mulo[b * 512 + o] = 1.0f / (1.0f + __expf(-s));
    else           addo[b * 512 + o] = s;
}

// ---------------- per-batch glob weights ----------------
__global__ __launch_bounds__(256) void scale_wglob(
    const float* __restrict__ fuw, const float* __restrict__ mulv, u16* __restrict__ wf)
{
    const int idx = blockIdx.x * 256 + threadIdx.x;   // 8*512*128
    const int cq = idx & 127;
    const int o  = (idx >> 7) & 511;
    const int b  = idx >> 16;
    const int c  = cq * 4;
    float4 w = *reinterpret_cast<const float4*>(&fuw[(size_t)o * 1024 + 512 + c]);
    float4 m = *reinterpret_cast<const float4*>(&mulv[b * 512 + c]);
    ushort4 u;
    u.x = f2bf(w.x * m.x); u.y = f2bf(w.y * m.y);
    u.z = f2bf(w.z * m.z); u.w = f2bf(w.w * m.w);
    *reinterpret_cast<ushort4*>(&wf[(size_t)b * 524288 + (size_t)o * 1024 + 512 + c]) = u;
}

// fb[b][o] = fu_b[o] + sum_c fu_w[o,c]*b3[c] + sum_c fu_w[o,512+c]*add[b,c]
__global__ __launch_bounds__(256) void fuse_bias(
    const float* __restrict__ fuw, const float* __restrict__ fub,
    const float* __restrict__ b3, const float* __restrict__ addv, float* __restrict__ fb)
{
    const int o = blockIdx.x * 256 + threadIdx.x;     // grid.x = 2
    const int b = blockIdx.y;
    const float* wr = fuw + (size_t)o * 1024;
    float s = fub[o];
    for (int c = 0; c < 512; c += 4) {
        float4 w1 = *reinterpret_cast<const float4*>(&wr[c]);
        float4 bv = *reinterpret_cast<const float4*>(&b3[c]);
        float4 w2 = *reinterpret_cast<const float4*>(&wr[512 + c]);
        float4 av = *reinterpret_cast<const float4*>(&addv[b * 512 + c]);
        s += w1.x * bv.x + w1.y * bv.y + w1.z * bv.z + w1.w * bv.w
           + w2.x * av.x + w2.y * av.y + w2.z * av.z + w2.w * av.w;
    }
    fb[b * 512 + o] = s;
}

// ---------------- wave-per-row softmax + exact top-k via 2-level radix histogram ----
// Each wave owns a private 2-replica 256-bin LDS histogram (no barriers: LDS ops
// are in-order per wave). Pass 1 bins the key top byte -> bin of the k-th key +
// exact count-above; pass 2 bins the low byte within that bin -> exact kt and
// a = #{km > kt}. No per-iteration wave-wide counts (the SALU/ballot storm of
// the binary-search versions is gone). Selection is bit-identical.
__global__ __launch_bounds__(256) void softmax_topk_wave(
    const u16* __restrict__ p, float* __restrict__ mxo,
    float* __restrict__ invSo, float* __restrict__ softo)
{
    __shared__ unsigned hist[4][2][260];
    const int w = threadIdx.x >> 6, l = threadIdx.x & 63;
    const int r = blockIdx.x * 4 + w;
    const int bc = blockIdx.y;
    const u16* pr = p + ((size_t)bc * NPIX + r) * NPIX;
    const uint4* p16 = reinterpret_cast<const uint4*>(pr);
    uint4 q0 = p16[l], q1 = p16[64 + l], q2 = p16[128 + l], q3 = p16[192 + l];
    uint2 q4 = reinterpret_cast<const uint2*>(pr)[512 + l];
    unsigned uw[18] = {q0.x, q0.y, q0.z, q0.w, q1.x, q1.y, q1.z, q1.w,
                       q2.x, q2.y, q2.z, q2.w, q3.x, q3.y, q3.z, q3.w,
                       q4.x, q4.y};
    unsigned km[36];
    #pragma unroll
    for (int i = 0; i < 18; ++i) {
        const unsigned v = uw[i];
        const unsigned m = ((v >> 15) & 0x10001u) * 0x7FFFu + 0x80008000u;
        const unsigned s = v ^ m;           // two sortable keys packed
        km[2 * i]     = s & 0xFFFFu;
        km[2 * i + 1] = s >> 16;
    }
    // row max
    unsigned kmax = km[0];
    #pragma unroll
    for (int i = 1; i < 36; ++i) kmax = max(kmax, km[i]);
    #pragma unroll
    for (int o = 32; o > 0; o >>= 1) kmax = max(kmax, (unsigned)__shfl_xor((int)kmax, o));
    const unsigned mxbits = (kmax & 0x8000u) ? (kmax ^ 0x8000u) : (kmax ^ 0xFFFFu);
    const float mx = bf2f((u16)mxbits);

    unsigned* h0 = &hist[w][0][0];
    unsigned* h1 = &hist[w][1][0];
    unsigned* hrep = (l & 1) ? h1 : h0;

    // ---- pass 1: top-byte histogram ----
    *reinterpret_cast<uint4*>(h0 + 4 * l) = make_uint4(0, 0, 0, 0);
    *reinterpret_cast<uint4*>(h1 + 4 * l) = make_uint4(0, 0, 0, 0);
    #pragma unroll
    for (int i = 0; i < 36; ++i) atomicAdd(&hrep[km[i] >> 8], 1u);
    uint4 c0 = *reinterpret_cast<const uint4*>(h0 + 4 * l);
    uint4 c1 = *reinterpret_cast<const uint4*>(h1 + 4 * l);
    {
        const unsigned b0 = c0.x + c1.x, b1 = c0.y + c1.y;
        const unsigned b2 = c0.z + c1.z, b3 = c0.w + c1.w;
        const unsigned part = b0 + b1 + b2 + b3;
        unsigned suf = part;
        #pragma unroll
        for (int o = 1; o < 64; o <<= 1) {
            const unsigned tt = __shfl_down(suf, o);
            if (l + o < 64) suf += tt;
        }
        const unsigned ab3 = suf - part;
        const unsigned ab2 = ab3 + b3, ab1 = ab2 + b2, ab0 = ab1 + b1;
        unsigned pk = 0;
        if (ab0 < KNUM && ab0 + b0 >= KNUM) pk = ((unsigned)(4 * l + 0) << 16) | ab0;
        if (ab1 < KNUM && ab1 + b1 >= KNUM) pk = ((unsigned)(4 * l + 1) << 16) | ab1;
        if (ab2 < KNUM && ab2 + b2 >= KNUM) pk = ((unsigned)(4 * l + 2) << 16) | ab2;
        if (ab3 < KNUM && ab3 + b3 >= KNUM) pk = ((unsigned)(4 * l + 3) << 16) | ab3;
        #pragma unroll
        for (int o = 32; o > 0; o >>= 1) pk = max(pk, (unsigned)__shfl_xor((int)pk, o));
        c0.x = pk;   // carry hb|aboveHb forward in c0.x
    }
    const unsigned hb = c0.x >> 16;
    const unsigned aboveHb = c0.x & 0xFFFFu;
    const int K2 = KNUM - (int)aboveHb;

    // ---- pass 2: low-byte histogram within top byte == hb ----
    *reinterpret_cast<uint4*>(h0 + 4 * l) = make_uint4(0, 0, 0, 0);
    *reinterpret_cast<uint4*>(h1 + 4 * l) = make_uint4(0, 0, 0, 0);
    #pragma unroll
    for (int i = 0; i < 36; ++i)
        if ((km[i] >> 8) == hb) atomicAdd(&hrep[km[i] & 0xFFu], 1u);
    uint4 d0 = *reinterpret_cast<const uint4*>(h0 + 4 * l);
    uint4 d1 = *reinterpret_cast<const uint4*>(h1 + 4 * l);
    unsigned pk2 = 0;
    {
        const unsigned b0 = d0.x + d1.x, b1 = d0.y + d1.y;
        const unsigned b2 = d0.z + d1.z, b3 = d0.w + d1.w;
        const unsigned part = b0 + b1 + b2 + b3;
        unsigned suf = part;
        #pragma unroll
        for (int o = 1; o < 64; o <<= 1) {
            const unsigned tt = __shfl_down(suf, o);
            if (l + o < 64) suf += tt;
        }
        const unsigned ab3 = suf - part;
        const unsigned ab2 = ab3 + b3, ab1 = ab2 + b2, ab0 = ab1 + b1;
        if ((int)ab0 < K2 && (int)(ab0 + b0) >= K2) pk2 = ((unsigned)(4 * l + 0) << 16) | ab0;
        if ((int)ab1 < K2 && (int)(ab1 + b1) >= K2) pk2 = ((unsigned)(4 * l + 1) << 16) | ab1;
        if ((int)ab2 < K2 && (int)(ab2 + b2) >= K2) pk2 = ((unsigned)(4 * l + 2) << 16) | ab2;
        if ((int)ab3 < K2 && (int)(ab3 + b3) >= K2) pk2 = ((unsigned)(4 * l + 3) << 16) | ab3;
        #pragma unroll
        for (int o = 32; o > 0; o >>= 1) pk2 = max(pk2, (unsigned)__shfl_xor((int)pk2, o));
    }
    const unsigned lb = pk2 >> 16;
    const unsigned aboveLb = pk2 & 0xFFFFu;
    const unsigned kt = (hb << 8) | lb;
    const int a = (int)(aboveHb + aboveLb);   // exact #{km > kt} over the row

    const unsigned tbits = (kt & 0x8000u) ? (kt ^ 0x8000u) : (kt ^ 0xFFFFu);
    const float te = __expf(bf2f((u16)tbits) - mx);
    // ---- final data pass: per-lane predicated adds, no cross-lane ops in loop ----
    float S = 0.f, ss = 0.f;
    #pragma unroll
    for (int i = 0; i < 36; ++i) {
        const unsigned bb = (km[i] & 0x8000u) ? (km[i] ^ 0x8000u) : (km[i] ^ 0xFFFFu);
        const float e = __expf(bf2f((u16)bb) - mx);
        S += e;
        if (km[i] > kt) ss += e;
    }
    #pragma unroll
    for (int o = 32; o > 0; o >>= 1) { S += __shfl_xor(S, o); ss += __shfl_xor(ss, o); }
    if (l == 0) {
        const size_t gi = (size_t)bc * NPIX + r;
        mxo[gi] = mx; invSo[gi] = 1.0f / S;
        softo[gi] = (ss + (float)(KNUM - a) * te) / (S * (float)KNUM);
    }
}

// colsum[b][j] = sum_i exp(p[i][j]-mx[i]) * invS[i]; i split 32 ways for occupancy.
__global__ __launch_bounds__(256) void colsum_k(
    const u16* __restrict__ p, const float* __restrict__ mxo,
    const float* __restrict__ invSo, float* __restrict__ colsum)
{
    const int j = blockIdx.x * 256 + threadIdx.x;
    const int ic0 = blockIdx.y * 72;
    const int bc = blockIdx.z;
    const float* mxr = mxo + (size_t)bc * NPIX;
    const float* isr = invSo + (size_t)bc * NPIX;
    const u16* pb = p + (size_t)bc * NPIX * NPIX;
    float s = 0.f;
    #pragma unroll 4
    for (int i = ic0; i < ic0 + 72; ++i)
        s += __expf(bf2f(pb[(size_t)i * NPIX + j]) - mxr[i]) * isr[i];
    atomicAdd(&colsum[(size_t)bc * NPIX + j], s);
}

__global__ __launch_bounds__(512) void ctx2_pool_k(
    const u16* __restrict__ qkv, const float* __restrict__ colsum,
    const float* __restrict__ soft, float* __restrict__ ctx2)
{
    const int c = threadIdx.x, b = blockIdx.y;
    const int nn0 = blockIdx.x * 128;
    float s = 0.f;
    for (int n = nn0; n < nn0 + 128; ++n) {
        const float wgt = colsum[(size_t)b * NPIX + n] * soft[(size_t)b * NPIX + n];
        s = fmaf(bf2f(qkv[((size_t)b * NPIX + n) * 768 + 256 + c]), wgt, s);
    }
    atomicAdd(&ctx2[b * NCH + c], s * (1.0f / (float)NPIX));
}

__global__ __launch_bounds__(256) void compute_z(
    const float* __restrict__ finw, const float* __restrict__ ctx2, float* __restrict__ z)
{
    const int o = blockIdx.x * 256 + threadIdx.x;
    const int b = blockIdx.y;
    const float* c2 = ctx2 + b * NCH;
    const float* wr = finw + (size_t)o * 1024 + 512;
    float s = 0.f;
    for (int c = 0; c < NCH; ++c) s = fmaf(wr[c], c2[c], s);
    z[b * NCH + o] = s;
}

// ---------------- host launcher ----------------
extern "C" void kernel_launch(void* const* d_in, const int* in_sizes, int n_in,
                              void* d_out, int out_size, void* d_ws, size_t ws_size,
                              hipStream_t stream)
{
    (void)in_sizes; (void)n_in; (void)out_size; (void)ws_size;
    const float* x      = (const float*)d_in[0];
    const float* lb_w1  = (const float*)d_in[1];
    const float* lb_g1  = (const float*)d_in[2];
    const float* lb_b1  = (const float*)d_in[3];
    const float* lb_w2  = (const float*)d_in[4];
    const float* lb_g2  = (const float*)d_in[5];
    const float* lb_b2  = (const float*)d_in[6];
    const float* lb_w3  = (const float*)d_in[7];
    const float* lb_g3  = (const float*)d_in[8];
    const float* lb_b3  = (const float*)d_in[9];
    const float* cm_w   = (const float*)d_in[10];
    // cm_b (d_in[11]) unused: softmax is shift-invariant to a scalar logit bias
    const float* ca_w1  = (const float*)d_in[12];
    const float* ca_b1  = (const float*)d_in[13];
    const float* ca_lg  = (const float*)d_in[14];
    const float* ca_lb  = (const float*)d_in[15];
    const float* ca_w2  = (const float*)d_in[16];
    const float* ca_b2  = (const float*)d_in[17];
    const float* cmu_w1 = (const float*)d_in[18];
    const float* cmu_b1 = (const float*)d_in[19];
    const float* cmu_lg = (const float*)d_in[20];
    const float* cmu_lb = (const float*)d_in[21];
    const float* cmu_w2 = (const float*)d_in[22];
    const float* cmu_b2 = (const float*)d_in[23];
    const float* fu_w   = (const float*)d_in[24];
    const float* fu_b   = (const float*)d_in[25];
    // 26..37 dead (region == 1 identically)
    const float* q_w    = (const float*)d_in[38];
    const float* k_w    = (const float*)d_in[39];
    const float* v_w    = (const float*)d_in[40];
    const float* fin_w  = (const float*)d_in[41];

    char* W = (char*)d_ws;
    const size_t SZ_ACT = (size_t)NB * NPIX * NCH * 2;     // 18,874,368 B
    u16* xb   = (u16*)(W);
    u16* bufA = (u16*)(W + SZ_ACT);                        // t1
    u16* bufB = (u16*)(W + 2 * SZ_ACT);                    // t2
    u16* gx   = (u16*)(W + 3 * SZ_ACT);
    u16* qkv  = (u16*)(W + 4 * SZ_ACT);                    // [b][n][768]
    u16* wfused = qkv;         // [8][512][1024] bf16, dead before qkv is written
    u16* pbuf = (u16*)(W + 4 * SZ_ACT + (size_t)NB * NPIX * 768 * 2);   // [8][N][N] bf16
    char* SM = (char*)(pbuf + (size_t)NB * NPIX * NPIX);
    float* logits = (float*)SM; SM += (size_t)NB * NPIX * 4;  // zero region start
    float* colsum = (float*)SM; SM += (size_t)NB * NPIX * 4;
    float* ctxb   = (float*)SM; SM += (size_t)NB * NCH * 4;
    float* ctx2b  = (float*)SM; SM += (size_t)NB * NCH * 4;   // zero region end
    float* maskb  = (float*)SM; SM += (size_t)NB * NPIX * 4;
    float* mxb    = (float*)SM; SM += (size_t)NB * NPIX * 4;
    float* invSb  = (float*)SM; SM += (size_t)NB * NPIX * 4;
    float* softb  = (float*)SM; SM += (size_t)NB * NPIX * 4;
    float* mulb   = (float*)SM; SM += (size_t)NB * NCH * 4;
    float* addb   = (float*)SM; SM += (size_t)NB * NCH * 4;
    float* zbuf   = (float*)SM; SM += (size_t)NB * NCH * 4;
    float* fbias  = (float*)SM; SM += (size_t)NB * NCH * 4;
    float* hnb    = (float*)SM; SM += (size_t)2 * NB * 128 * 4;
    float* wfold  = (float*)SM; SM += (size_t)9 * NCH * 4;
    u16* w1b   = (u16*)SM; SM += (size_t)512 * 512 * 2;
    u16* fuwb  = (u16*)SM; SM += (size_t)512 * 1024 * 2;
    u16* finwb = (u16*)SM; SM += (size_t)512 * 1024 * 2;
    u16* qkvwb = (u16*)SM; SM += (size_t)768 * 512 * 2;
    u16* w3t   = (u16*)SM; SM += (size_t)512 * 512 * 2;

    const float invs  = 0.99999500003749978f;   // 1/sqrt(1+1e-5)
    const float rs128 = 0.08838834764831845f;   // 1/sqrt(128)
    const long SACT = (long)NPIX * NCH;

    // zero logits/colsum/ctx/ctx2 first (logits accumulated by atomics)
    hipMemsetAsync(logits, 0,
        ((size_t)2 * NB * NPIX + (size_t)2 * NB * NCH) * 4, stream);
    // weight conversions in one dispatch
    prep_weights<<<1683, 256, 0, stream>>>(lb_w1, fu_w, fin_w, q_w, k_w, v_w,
        lb_w2, lb_g2, w1b, fuwb, finwb, qkvwb, wfold);
    transpose_cvt_ml<<<dim3(36, 8, 8), 256, 0, stream>>>(x, cm_w, xb, logits);
    transpose_w3<<<dim3(8, 8), 256, 0, stream>>>(lb_w3, lb_g3, w3t);

    // W'' = (fu_local . diag(g3*invs)) @ w3  -> wfused[:, :512] (8 replicas)
    mfma_gemm<<<dim3(4, 4, 8), 256, 0, stream>>>(w3t, 512, 0, fuwb, nullptr, 1024, 0,
        wfused, 1024, 524288, nullptr, nullptr, nullptr, 0, nullptr, 0, 512, 1.0f, 0);

    // local branch start: t1 = relu(bn(W1 @ x)); t2 = relu(bn(dw3x3(t1)))
    mfma_gemm<<<dim3(18, 4, 8), 256, 0, stream>>>(w1b, 512, 0, xb, nullptr, 512, SACT,
        bufA, 512, SACT, lb_g1, lb_b1, nullptr, 0, nullptr, 0, 512, invs, 1);
    dwconv_k<<<9216, 256, 0, stream>>>(bufA, wfold, lb_b2, bufB);
    // ContextBlock
    softmax_mask<<<8, 256, 0, stream>>>(logits, maskb);
    ctx_pool_k<<<dim3(18, 8), 512, 0, stream>>>(xb, maskb, ctxb);
    chan_h<<<512, 256, 0, stream>>>(ctxb, cmu_w1, cmu_b1, ca_w1, ca_b1, hnb);
    chan_ln<<<dim3(2, 8), 128, 0, stream>>>(cmu_lg, cmu_lb, ca_lg, ca_lb, hnb);
    chan_o<<<dim3(4, 2, 8), 128, 0, stream>>>(hnb, cmu_w2, cmu_b2, ca_w2, ca_b2, mulb, addb);
    // per-batch glob weights + fused bias
    scale_wglob<<<2048, 256, 0, stream>>>(fu_w, mulb, wfused);
    fuse_bias<<<dim3(2, 8), 256, 0, stream>>>(fu_w, fu_b, lb_b3, addb, fbias);
    // fused gx GEMM: gx = W''@t2 + (fu_glob.mul_b)@x + fbias
    mfma_gemm<<<dim3(18, 4, 8), 256, 0, stream>>>(wfused, 1024, 524288, bufB, xb, 512, SACT,
        gx, 512, SACT, nullptr, nullptr, nullptr, 0, fbias, 512, 1024, 1.0f, 0);
    // q|k|v stacked projection (overwrites wfused region - wfused is dead)
    mfma_gemm<<<dim3(18, 6, 8), 256, 0, stream>>>(qkvwb, 512, 0, gx, nullptr, 512, SACT,
        qkv, 768, (long)NPIX * 768, nullptr, nullptr, nullptr, 0, nullptr, 0, 512, 1.0f, 0);
    // attention: single 8-batch pass
    mfma_gemm<<<dim3(18, 18, 8), 256, 0, stream>>>(qkv + 128, 768, (long)NPIX * 768,
        qkv, nullptr, 768, (long)NPIX * 768,
        pbuf, NPIX, (long)NPIX * NPIX, nullptr, nullptr, nullptr, 0, nullptr, 0,
        128, rs128, 0);
    softmax_topk_wave<<<dim3(576, 8), 256, 0, stream>>>(pbuf, mxb, invSb, softb);
    colsum_k<<<dim3(9, 32, 8), 256, 0, stream>>>(pbuf, mxb, invSb, colsum);
    // epilogue path
    ctx2_pool_k<<<dim3(18, 8), 512, 0, stream>>>(qkv, colsum, softb, ctx2b);
    compute_z<<<dim3(2, 8), 256, 0, stream>>>(fin_w, ctx2b, zbuf);
    mfma_gemm<<<dim3(4, 18, 8), 256, 0, stream>>>(gx, 512, SACT, finwb, nullptr, 1024, 0,
        d_out, NPIX, (long)NCH * NPIX, nullptr, nullptr, zbuf, 512, nullptr, 0,
        512, 1.0f, 2);
}

// Round 12
// 386.222 us; speedup vs baseline: 1.0490x; 1.0079x over previous
//
#include <hip/hip_runtime.h>
#include <math.h>

#define NPIX 2304
#define NCH  512
#define NB   8
#define KNUM 230

typedef unsigned short u16;
typedef __attribute__((ext_vector_type(8))) short short8v;
typedef __attribute__((ext_vector_type(4))) float float4v;

__device__ __forceinline__ float bf2f(u16 u) {
    union { unsigned v; float f; } x; x.v = ((unsigned)u) << 16; return x.f;
}
__device__ __forceinline__ u16 f2bf(float f) {
    union { float f; unsigned v; } x; x.f = f;
    unsigned r = x.v + 0x7FFFu + ((x.v >> 16) & 1u);   // RNE
    return (u16)(r >> 16);
}

// ---------------- reductions ----------------
__device__ __forceinline__ float waveSum(float v) {
    #pragma unroll
    for (int o = 32; o > 0; o >>= 1) v += __shfl_down(v, o);
    return v;
}
__device__ __forceinline__ float blockSum256(float v, float* sc4) {
    v = waveSum(v);
    __syncthreads();
    if ((threadIdx.x & 63) == 0) sc4[threadIdx.x >> 6] = v;
    __syncthreads();
    return sc4[0] + sc4[1] + sc4[2] + sc4[3];
}
__device__ __forceinline__ float waveMaxF(float v) {
    #pragma unroll
    for (int o = 32; o > 0; o >>= 1) v = fmaxf(v, __shfl_down(v, o));
    return v;
}
__device__ __forceinline__ float blockMax256(float v, float* sc4) {
    v = waveMaxF(v);
    __syncthreads();
    if ((threadIdx.x & 63) == 0) sc4[threadIdx.x >> 6] = v;
    __syncthreads();
    return fmaxf(fmaxf(sc4[0], sc4[1]), fmaxf(sc4[2], sc4[3]));
}

// ---------------- async global->LDS 16B ----------------
__device__ __forceinline__ void gl_lds16(const u16* g, u16* l) {
    __builtin_amdgcn_global_load_lds(
        reinterpret_cast<const unsigned __attribute__((address_space(1)))*>(
            reinterpret_cast<uintptr_t>(g)),
        reinterpret_cast<unsigned __attribute__((address_space(3)))*>(
            reinterpret_cast<uintptr_t>(l)),
        16, 0, 0);
}

// ---------------- bf16 MFMA GEMM ----------------
// D[R, Cl] = alpha*scaleR[R]*sum_k A[R,k]*B[Cl,k] + biasR[R] + biasC[b,Cl] + biasRB[b,R]
// A, B row-major, k contiguous. Output stored out[b][Cl][R] (R contiguous).
// flags: 1 = relu, 2 = fp32 output (else bf16). B1: source for k >= 512 (concat).
__global__ __launch_bounds__(256, 3) void mfma_gemm(
    const u16* __restrict__ A, int ldA, long sA,
    const u16* __restrict__ B0, const u16* __restrict__ B1, int ldB, long sB,
    void* __restrict__ outp, int ldO, long sO,
    const float* __restrict__ scaleR, const float* __restrict__ biasR,
    const float* __restrict__ biasC, int ldbc,
    const float* __restrict__ biasRB, int ldrb,
    int K, float alpha, int flags)
{
    __shared__ u16 lA[128 * 64];
    __shared__ u16 lB[128 * 64];
    const int t  = threadIdx.x;
    const int w  = t >> 6, l = t & 63;
    const int wR = w >> 1, wC = w & 1;
    const int lg = l >> 4, lr = l & 15, l7 = l & 7;
    const int b   = blockIdx.z;
    const int Cl0 = blockIdx.x * 128;
    const int R0  = blockIdx.y * 128;
    const u16* Ab  = A + (size_t)b * sA;
    const u16* B0b = B0 + (size_t)b * sB;
    const u16* B1b = B1 ? B1 + (size_t)b * sB : nullptr;

    float4v acc[4][4];
    const float4v zero = {0.f, 0.f, 0.f, 0.f};
    #pragma unroll
    for (int i = 0; i < 4; ++i)
        #pragma unroll
        for (int j = 0; j < 4; ++j) acc[i][j] = zero;

    const int sr = t >> 3;     // staging row-in-issue (0..31)
    const int sp = t & 7;      // physical 16B chunk

    for (int k0 = 0; k0 < K; k0 += 64) {
        const u16* Bsrc = B0b; int kb = k0;
        if (B1b && k0 >= 512) { Bsrc = B1b; kb = k0 - 512; }
        #pragma unroll
        for (int i = 0; i < 4; ++i) {
            const int r  = i * 32 + sr;
            const int ca = sp ^ (r & 7);                  // pre-swizzled source chunk
            gl_lds16(Ab   + (size_t)(R0  + r) * ldA + (k0 + ca * 8), &lA[i * 2048 + t * 8]);
            gl_lds16(Bsrc + (size_t)(Cl0 + r) * ldB + (kb + ca * 8), &lB[i * 2048 + t * 8]);
        }
        __syncthreads();
        #pragma unroll
        for (int kk = 0; kk < 2; ++kk) {
            short8v af[4], bfv[4];
            const int p = (kk * 4 + lg) ^ l7;             // swizzled read chunk
            #pragma unroll
            for (int mt = 0; mt < 4; ++mt) {
                const int rA = wR * 64 + mt * 16 + lr;
                af[mt]  = *reinterpret_cast<const short8v*>(&lA[rA * 64 + p * 8]);
                const int rB = wC * 64 + mt * 16 + lr;
                bfv[mt] = *reinterpret_cast<const short8v*>(&lB[rB * 64 + p * 8]);
            }
            #pragma unroll
            for (int mt = 0; mt < 4; ++mt)
                #pragma unroll
                for (int nt = 0; nt < 4; ++nt)
                    acc[mt][nt] = __builtin_amdgcn_mfma_f32_16x16x32_bf16(
                        af[mt], bfv[nt], acc[mt][nt], 0, 0, 0);
        }
        __syncthreads();
    }

    const bool relu = (flags & 1), f32o = (flags & 2);
    #pragma unroll
    for (int nt = 0; nt < 4; ++nt) {
        const int Cl = Cl0 + wC * 64 + nt * 16 + lr;
        const float bc = biasC ? biasC[(size_t)b * ldbc + Cl] : 0.f;
        #pragma unroll
        for (int mt = 0; mt < 4; ++mt) {
            const int Rb = R0 + wR * 64 + mt * 16 + lg * 4;
            float4 scv = scaleR ? *reinterpret_cast<const float4*>(&scaleR[Rb])
                                : make_float4(1.f, 1.f, 1.f, 1.f);
            float4 bv  = biasR  ? *reinterpret_cast<const float4*>(&biasR[Rb])
                                : make_float4(0.f, 0.f, 0.f, 0.f);
            float4 rbv = biasRB ? *reinterpret_cast<const float4*>(&biasRB[(size_t)b * ldrb + Rb])
                                : make_float4(0.f, 0.f, 0.f, 0.f);
            float vals[4];
            #pragma unroll
            for (int j = 0; j < 4; ++j) {
                const float sc = alpha * ((&scv.x)[j]);
                float v = acc[mt][nt][j] * sc + (&bv.x)[j] + bc + (&rbv.x)[j];
                if (relu) v = fmaxf(v, 0.f);
                vals[j] = v;
            }
            if (f32o) {
                float* op = (float*)outp + (size_t)b * sO + (size_t)Cl * ldO + Rb;
                *reinterpret_cast<float4*>(op) = make_float4(vals[0], vals[1], vals[2], vals[3]);
            } else {
                ushort4 u;
                u.x = f2bf(vals[0]); u.y = f2bf(vals[1]);
                u.z = f2bf(vals[2]); u.w = f2bf(vals[3]);
                u16* op = (u16*)outp + (size_t)b * sO + (size_t)Cl * ldO + Rb;
                *reinterpret_cast<ushort4*>(op) = u;
            }
        }
    }
}

// ---------------- transpose+convert x + fused mask-logit partial dot ----------------
__global__ __launch_bounds__(256) void transpose_cvt_ml(
    const float* __restrict__ x, const float* __restrict__ cmw,
    u16* __restrict__ xb, float* __restrict__ logits)
{
    __shared__ float tile[64][65];
    const int t = threadIdx.x;
    const int n0 = blockIdx.x * 64, c0 = blockIdx.y * 64, b = blockIdx.z;
    const int tr = t >> 4, tc4 = (t & 15) * 4;
    #pragma unroll
    for (int i = 0; i < 4; ++i) {
        const int cc = tr + i * 16;
        float4 v = *reinterpret_cast<const float4*>(
            x + ((size_t)(b * NCH + c0 + cc)) * NPIX + n0 + tc4);
        tile[cc][tc4 + 0] = v.x; tile[cc][tc4 + 1] = v.y;
        tile[cc][tc4 + 2] = v.z; tile[cc][tc4 + 3] = v.w;
    }
    __syncthreads();
    #pragma unroll
    for (int i = 0; i < 4; ++i) {
        const int nn = tr + i * 16;
        ushort4 u;
        u.x = f2bf(tile[tc4 + 0][nn]); u.y = f2bf(tile[tc4 + 1][nn]);
        u.z = f2bf(tile[tc4 + 2][nn]); u.w = f2bf(tile[tc4 + 3][nn]);
        *reinterpret_cast<ushort4*>(xb + ((size_t)b * NPIX + n0 + nn) * NCH + c0 + tc4) = u;
    }
    const int nl = t >> 2, q = t & 3;
    float s = 0.f;
    #pragma unroll
    for (int k = 0; k < 16; ++k) {
        const int cc = q * 16 + k;
        s = fmaf(tile[cc][nl], cmw[c0 + cc], s);
    }
    s += __shfl_xor(s, 1);
    s += __shfl_xor(s, 2);
    if (q == 0) atomicAdd(&logits[(size_t)b * NPIX + n0 + nl], s);
}

// ---------------- w3T scaled: w3t[k][c] = lb_w3[c][k] * g3[c] * invs, bf16 ----------------
__global__ __launch_bounds__(256) void transpose_w3(
    const float* __restrict__ w3, const float* __restrict__ g3, u16* __restrict__ w3t)
{
    __shared__ float tile[64][65];
    const int t = threadIdx.x;
    const int k0 = blockIdx.x * 64, c0 = blockIdx.y * 64;
    const int tr = t >> 4, tc4 = (t & 15) * 4;
    #pragma unroll
    for (int i = 0; i < 4; ++i) {
        const int cc = tr + i * 16;
        const float s = g3[c0 + cc] * 0.99999500003749978f;
        float4 v = *reinterpret_cast<const float4*>(&w3[(size_t)(c0 + cc) * 512 + k0 + tc4]);
        tile[cc][tc4 + 0] = v.x * s; tile[cc][tc4 + 1] = v.y * s;
        tile[cc][tc4 + 2] = v.z * s; tile[cc][tc4 + 3] = v.w * s;
    }
    __syncthreads();
    #pragma unroll
    for (int i = 0; i < 4; ++i) {
        const int kk = tr + i * 16;
        ushort4 u;
        u.x = f2bf(tile[tc4 + 0][kk]); u.y = f2bf(tile[tc4 + 1][kk]);
        u.z = f2bf(tile[tc4 + 2][kk]); u.w = f2bf(tile[tc4 + 3][kk]);
        *reinterpret_cast<ushort4*>(&w3t[(size_t)(k0 + kk) * 512 + c0 + tc4]) = u;
    }
}

// ---------------- all weight conversions in one dispatch ----------------
__device__ __forceinline__ void cvt4(const float* s, u16* d, int i) {
    float4 v = reinterpret_cast<const float4*>(s)[i];
    ushort4 u; u.x = f2bf(v.x); u.y = f2bf(v.y); u.z = f2bf(v.z); u.w = f2bf(v.w);
    reinterpret_cast<ushort4*>(d)[i] = u;
}
__global__ __launch_bounds__(256) void prep_weights(
    const float* __restrict__ w1, const float* __restrict__ fu,
    const float* __restrict__ fin, const float* __restrict__ qw,
    const float* __restrict__ kw, const float* __restrict__ vw,
    const float* __restrict__ dww, const float* __restrict__ dwg,
    u16* __restrict__ w1b, u16* __restrict__ fuwb, u16* __restrict__ finwb,
    u16* __restrict__ qkvwb, float* __restrict__ wfold)
{
    const int i = blockIdx.x * 256 + threadIdx.x;
    if (i < 65536)            cvt4(w1, w1b, i);
    else if (i < 196608)      cvt4(fu, fuwb, i - 65536);
    else if (i < 327680)      cvt4(fin, finwb, i - 196608);
    else if (i < 344064)      cvt4(qw, qkvwb, i - 327680);
    else if (i < 360448)      cvt4(kw, qkvwb + 128 * 512, i - 344064);
    else if (i < 425984)      cvt4(vw, qkvwb + 256 * 512, i - 360448);
    else if (i < 425984 + 4608) {
        const int j = i - 425984;
        const int c = j / 9, tap = j % 9;
        wfold[tap * NCH + c] = dww[j] * dwg[c] * 0.99999500003749978f;
    }
}

// ---------------- depthwise 3x3 + BN + ReLU, [n][c] bf16 ----------------
__global__ __launch_bounds__(256) void dwconv_k(
    const u16* __restrict__ t1, const float* __restrict__ wf,
    const float* __restrict__ b2, u16* __restrict__ t2)
{
    const int idx = blockIdx.x * 256 + threadIdx.x;
    const int cq = idx & 127;
    const int n  = (idx >> 7) % NPIX;
    const int b  = (idx >> 7) / NPIX;
    const int c  = cq * 4;
    const int y = n / 48, x = n % 48;
    float s0 = 0.f, s1 = 0.f, s2 = 0.f, s3 = 0.f;
    #pragma unroll
    for (int dy = -1; dy <= 1; ++dy) {
        const int yy = y + dy;
        if (yy < 0 || yy >= 48) continue;
        #pragma unroll
        for (int dx = -1; dx <= 1; ++dx) {
            const int xx = x + dx;
            if (xx < 0 || xx >= 48) continue;
            ushort4 tv = *reinterpret_cast<const ushort4*>(
                &t1[((size_t)b * NPIX + yy * 48 + xx) * NCH + c]);
            float4 wv = *reinterpret_cast<const float4*>(
                &wf[((dy + 1) * 3 + dx + 1) * NCH + c]);
            s0 = fmaf(bf2f(tv.x), wv.x, s0); s1 = fmaf(bf2f(tv.y), wv.y, s1);
            s2 = fmaf(bf2f(tv.z), wv.z, s2); s3 = fmaf(bf2f(tv.w), wv.w, s3);
        }
    }
    float4 bb = *reinterpret_cast<const float4*>(&b2[c]);
    ushort4 o;
    o.x = f2bf(fmaxf(s0 + bb.x, 0.f)); o.y = f2bf(fmaxf(s1 + bb.y, 0.f));
    o.z = f2bf(fmaxf(s2 + bb.z, 0.f)); o.w = f2bf(fmaxf(s3 + bb.w, 0.f));
    *reinterpret_cast<ushort4*>(&t2[((size_t)b * NPIX + n) * NCH + c]) = o;
}

// ---------------- ContextBlock ----------------
__global__ __launch_bounds__(256) void softmax_mask(
    const float* __restrict__ logits, float* __restrict__ mask)
{
    __shared__ float sc[4];
    const int b = blockIdx.x, t = threadIdx.x;
    const float* lr = logits + (size_t)b * NPIX;
    float mx = -3.4e38f;
    for (int i = t; i < NPIX; i += 256) mx = fmaxf(mx, lr[i]);
    mx = blockMax256(mx, sc);
    float s = 0.f;
    for (int i = t; i < NPIX; i += 256) s += __expf(lr[i] - mx);
    s = blockSum256(s, sc);
    const float inv = 1.0f / s;
    for (int i = t; i < NPIX; i += 256) mask[(size_t)b * NPIX + i] = __expf(lr[i] - mx) * inv;
}

__global__ __launch_bounds__(512) void ctx_pool_k(
    const u16* __restrict__ xb, const float* __restrict__ mask, float* __restrict__ ctx)
{
    const int c = threadIdx.x, b = blockIdx.y;
    const int nn0 = blockIdx.x * 128;
    float s = 0.f;
    for (int n = nn0; n < nn0 + 128; ++n)
        s = fmaf(bf2f(xb[((size_t)b * NPIX + n) * NCH + c]), mask[(size_t)b * NPIX + n], s);
    atomicAdd(&ctx[b * NCH + c], s);
}

// ---------------- channel MLP: 3 stages, wave-per-dot parallelism ----------------
__global__ __launch_bounds__(256) void chan_h(
    const float* __restrict__ ctxv,
    const float* __restrict__ mw1, const float* __restrict__ mb1,
    const float* __restrict__ aw1, const float* __restrict__ ab1,
    float* __restrict__ hnb)
{
    const int w = threadIdx.x >> 6, l = threadIdx.x & 63;
    const int gid = blockIdx.x * 4 + w;          // 0..2047
    const int path = gid >> 10;
    const int rem  = gid & 1023;
    const int h = rem >> 3, b = rem & 7;
    const float* W1 = path ? aw1 : mw1;
    const float* B1 = path ? ab1 : mb1;
    const float4 wa = *reinterpret_cast<const float4*>(&W1[h * 512 + l * 8]);
    const float4 wb = *reinterpret_cast<const float4*>(&W1[h * 512 + l * 8 + 4]);
    const float4 ca = *reinterpret_cast<const float4*>(&ctxv[b * 512 + l * 8]);
    const float4 cb = *reinterpret_cast<const float4*>(&ctxv[b * 512 + l * 8 + 4]);
    float s = wa.x * ca.x + wa.y * ca.y + wa.z * ca.z + wa.w * ca.w
            + wb.x * cb.x + wb.y * cb.y + wb.z * cb.z + wb.w * cb.w;
    s = waveSum(s);
    if (l == 0) hnb[(path * 8 + b) * 128 + h] = s + B1[h];
}

__global__ __launch_bounds__(128) void chan_ln(
    const float* __restrict__ mlg, const float* __restrict__ mlb,
    const float* __restrict__ alg, const float* __restrict__ alb,
    float* __restrict__ hnb)
{
    __shared__ float sc[2];
    const int path = blockIdx.x, b = blockIdx.y, t = threadIdx.x;
    float* hp = hnb + (path * 8 + b) * 128;
    const float v = hp[t];
    float s1 = waveSum(v);
    if ((t & 63) == 0) sc[t >> 6] = s1;
    __syncthreads();
    const float mu = (sc[0] + sc[1]) * (1.0f / 128.0f);
    const float d = v - mu;
    float s2 = waveSum(d * d);
    __syncthreads();
    if ((t & 63) == 0) sc[t >> 6] = s2;
    __syncthreads();
    const float var = (sc[0] + sc[1]) * (1.0f / 128.0f);
    const float* LG = path ? alg : mlg;
    const float* LB = path ? alb : mlb;
    hp[t] = fmaxf(d / sqrtf(var + 1e-5f) * LG[t] + LB[t], 0.f);
}

__global__ __launch_bounds__(128) void chan_o(
    const float* __restrict__ hnb,
    const float* __restrict__ mw2, const float* __restrict__ mb2,
    const float* __restrict__ aw2, const float* __restrict__ ab2,
    float* __restrict__ mulo, float* __restrict__ addo)
{
    __shared__ float hs[128];
    const int oc = blockIdx.x, path = blockIdx.y, b = blockIdx.z;
    const int t = threadIdx.x;
    hs[t] = hnb[(path * 8 + b) * 128 + t];
    __syncthreads();
    const int o = oc * 128 + t;
    const float* W2 = path ? aw2 : mw2;
    float s = (path ? ab2 : mb2)[o];
    #pragma unroll
    for (int p = 0; p < 128; p += 4) {
        const float4 wv = *reinterpret_cast<const float4*>(&W2[o * 128 + p]);
        s += wv.x * hs[p] + wv.y * hs[p + 1] + wv.z * hs[p + 2] + wv.w * hs[p + 3];
    }
    if (path == 0) mulo[b * 512 + o] = 1.0f / (1.0f + __expf(-s));
    else           addo[b * 512 + o] = s;
}

// ---------------- per-batch glob weights ----------------
__global__ __launch_bounds__(256) void scale_wglob(
    const float* __restrict__ fuw, const float* __restrict__ mulv, u16* __restrict__ wf)
{
    const int idx = blockIdx.x * 256 + threadIdx.x;   // 8*512*128
    const int cq = idx & 127;
    const int o  = (idx >> 7) & 511;
    const int b  = idx >> 16;
    const int c  = cq * 4;
    float4 w = *reinterpret_cast<const float4*>(&fuw[(size_t)o * 1024 + 512 + c]);
    float4 m = *reinterpret_cast<const float4*>(&mulv[b * 512 + c]);
    ushort4 u;
    u.x = f2bf(w.x * m.x); u.y = f2bf(w.y * m.y);
    u.z = f2bf(w.z * m.z); u.w = f2bf(w.w * m.w);
    *reinterpret_cast<ushort4*>(&wf[(size_t)b * 524288 + (size_t)o * 1024 + 512 + c]) = u;
}

// fb[b][o] = fu_b[o] + sum_c fu_w[o,c]*b3[c] + sum_c fu_w[o,512+c]*add[b,c]
__global__ __launch_bounds__(256) void fuse_bias(
    const float* __restrict__ fuw, const float* __restrict__ fub,
    const float* __restrict__ b3, const float* __restrict__ addv, float* __restrict__ fb)
{
    const int o = blockIdx.x * 256 + threadIdx.x;     // grid.x = 2
    const int b = blockIdx.y;
    const float* wr = fuw + (size_t)o * 1024;
    float s = fub[o];
    for (int c = 0; c < 512; c += 4) {
        float4 w1 = *reinterpret_cast<const float4*>(&wr[c]);
        float4 bv = *reinterpret_cast<const float4*>(&b3[c]);
        float4 w2 = *reinterpret_cast<const float4*>(&wr[512 + c]);
        float4 av = *reinterpret_cast<const float4*>(&addv[b * 512 + c]);
        s += w1.x * bv.x + w1.y * bv.y + w1.z * bv.z + w1.w * bv.w
           + w2.x * av.x + w2.y * av.y + w2.z * av.z + w2.w * av.w;
    }
    fb[b * 512 + o] = s;
}

// ---------------- wave-per-row softmax + exact top-k on bf16 keys ----------------
// (round-8 form: plain ballot counting -- measured best of 4 variants)
__global__ __launch_bounds__(256) void softmax_topk_wave(
    const u16* __restrict__ p, float* __restrict__ mxo,
    float* __restrict__ invSo, float* __restrict__ softo)
{
    const int w = threadIdx.x >> 6, l = threadIdx.x & 63;
    const int r = blockIdx.x * 4 + w;
    const int bc = blockIdx.y;
    const u16* pr = p + ((size_t)bc * NPIX + r) * NPIX;
    const uint4* p16 = reinterpret_cast<const uint4*>(pr);
    uint4 q0 = p16[l], q1 = p16[64 + l], q2 = p16[128 + l], q3 = p16[192 + l];
    uint2 q4 = reinterpret_cast<const uint2*>(pr)[512 + l];
    unsigned uw[18] = {q0.x, q0.y, q0.z, q0.w, q1.x, q1.y, q1.z, q1.w,
                       q2.x, q2.y, q2.z, q2.w, q3.x, q3.y, q3.z, q3.w,
                       q4.x, q4.y};
    unsigned km[36];
    #pragma unroll
    for (int i = 0; i < 18; ++i) {
        const unsigned v = uw[i];
        const unsigned m = ((v >> 15) & 0x10001u) * 0x7FFFu + 0x80008000u;
        const unsigned s = v ^ m;           // two sortable keys packed
        km[2 * i]     = s & 0xFFFFu;
        km[2 * i + 1] = s >> 16;
    }
    unsigned kmax = km[0];
    #pragma unroll
    for (int i = 1; i < 36; ++i) kmax = max(kmax, km[i]);
    #pragma unroll
    for (int o = 32; o > 0; o >>= 1) kmax = max(kmax, (unsigned)__shfl_xor((int)kmax, o));
    const unsigned mxbits = (kmax & 0x8000u) ? (kmax ^ 0x8000u) : (kmax ^ 0xFFFFu);
    const float mx = bf2f((u16)mxbits);
    unsigned kt = 0u;
    for (int bit = 15; bit >= 0; --bit) {
        const unsigned cand = kt | (1u << bit);
        int c = 0;
        #pragma unroll
        for (int i = 0; i < 36; ++i)
            c += (int)__popcll(__ballot(km[i] >= cand));
        if (c >= KNUM) kt = cand;
    }
    const unsigned tbits = (kt & 0x8000u) ? (kt ^ 0x8000u) : (kt ^ 0xFFFFu);
    const float te = __expf(bf2f((u16)tbits) - mx);
    float S = 0.f, ss = 0.f; int a = 0;
    #pragma unroll
    for (int i = 0; i < 36; ++i) {
        const unsigned bb = (km[i] & 0x8000u) ? (km[i] ^ 0x8000u) : (km[i] ^ 0xFFFFu);
        const float e = __expf(bf2f((u16)bb) - mx);
        S += e;
        const bool gt = km[i] > kt;
        if (gt) ss += e;
        a += (int)__popcll(__ballot(gt));
    }
    #pragma unroll
    for (int o = 32; o > 0; o >>= 1) { S += __shfl_xor(S, o); ss += __shfl_xor(ss, o); }
    if (l == 0) {
        const size_t gi = (size_t)bc * NPIX + r;
        mxo[gi] = mx; invSo[gi] = 1.0f / S;
        softo[gi] = (ss + (float)(KNUM - a) * te) / (S * (float)KNUM);
    }
}

// colsum[b][j] = sum_i exp(p[i][j]-mx[i]) * invS[i]; i split 32 ways for occupancy.
__global__ __launch_bounds__(256) void colsum_k(
    const u16* __restrict__ p, const float* __restrict__ mxo,
    const float* __restrict__ invSo, float* __restrict__ colsum)
{
    const int j = blockIdx.x * 256 + threadIdx.x;
    const int ic0 = blockIdx.y * 72;
    const int bc = blockIdx.z;
    const float* mxr = mxo + (size_t)bc * NPIX;
    const float* isr = invSo + (size_t)bc * NPIX;
    const u16* pb = p + (size_t)bc * NPIX * NPIX;
    float s = 0.f;
    #pragma unroll 4
    for (int i = ic0; i < ic0 + 72; ++i)
        s += __expf(bf2f(pb[(size_t)i * NPIX + j]) - mxr[i]) * isr[i];
    atomicAdd(&colsum[(size_t)bc * NPIX + j], s);
}

__global__ __launch_bounds__(512) void ctx2_pool_k(
    const u16* __restrict__ qkv, const float* __restrict__ colsum,
    const float* __restrict__ soft, float* __restrict__ ctx2)
{
    const int c = threadIdx.x, b = blockIdx.y;
    const int nn0 = blockIdx.x * 128;
    float s = 0.f;
    for (int n = nn0; n < nn0 + 128; ++n) {
        const float wgt = colsum[(size_t)b * NPIX + n] * soft[(size_t)b * NPIX + n];
        s = fmaf(bf2f(qkv[((size_t)b * NPIX + n) * 768 + 256 + c]), wgt, s);
    }
    atomicAdd(&ctx2[b * NCH + c], s * (1.0f / (float)NPIX));
}

__global__ __launch_bounds__(256) void compute_z(
    const float* __restrict__ finw, const float* __restrict__ ctx2, float* __restrict__ z)
{
    const int o = blockIdx.x * 256 + threadIdx.x;
    const int b = blockIdx.y;
    const float* c2 = ctx2 + b * NCH;
    const float* wr = finw + (size_t)o * 1024 + 512;
    float s = 0.f;
    for (int c = 0; c < NCH; ++c) s = fmaf(wr[c], c2[c], s);
    z[b * NCH + o] = s;
}

// ---------------- host launcher ----------------
extern "C" void kernel_launch(void* const* d_in, const int* in_sizes, int n_in,
                              void* d_out, int out_size, void* d_ws, size_t ws_size,
                              hipStream_t stream)
{
    (void)in_sizes; (void)n_in; (void)out_size; (void)ws_size;
    const float* x      = (const float*)d_in[0];
    const float* lb_w1  = (const float*)d_in[1];
    const float* lb_g1  = (const float*)d_in[2];
    const float* lb_b1  = (const float*)d_in[3];
    const float* lb_w2  = (const float*)d_in[4];
    const float* lb_g2  = (const float*)d_in[5];
    const float* lb_b2  = (const float*)d_in[6];
    const float* lb_w3  = (const float*)d_in[7];
    const float* lb_g3  = (const float*)d_in[8];
    const float* lb_b3  = (const float*)d_in[9];
    const float* cm_w   = (const float*)d_in[10];
    // cm_b (d_in[11]) unused: softmax is shift-invariant to a scalar logit bias
    const float* ca_w1  = (const float*)d_in[12];
    const float* ca_b1  = (const float*)d_in[13];
    const float* ca_lg  = (const float*)d_in[14];
    const float* ca_lb  = (const float*)d_in[15];
    const float* ca_w2  = (const float*)d_in[16];
    const float* ca_b2  = (const float*)d_in[17];
    const float* cmu_w1 = (const float*)d_in[18];
    const float* cmu_b1 = (const float*)d_in[19];
    const float* cmu_lg = (const float*)d_in[20];
    const float* cmu_lb = (const float*)d_in[21];
    const float* cmu_w2 = (const float*)d_in[22];
    const float* cmu_b2 = (const float*)d_in[23];
    const float* fu_w   = (const float*)d_in[24];
    const float* fu_b   = (const float*)d_in[25];
    // 26..37 dead (region == 1 identically)
    const float* q_w    = (const float*)d_in[38];
    const float* k_w    = (const float*)d_in[39];
    const float* v_w    = (const float*)d_in[40];
    const float* fin_w  = (const float*)d_in[41];

    char* W = (char*)d_ws;
    const size_t SZ_ACT = (size_t)NB * NPIX * NCH * 2;     // 18,874,368 B
    u16* xb   = (u16*)(W);
    u16* bufA = (u16*)(W + SZ_ACT);                        // t1
    u16* bufB = (u16*)(W + 2 * SZ_ACT);                    // t2
    u16* gx   = (u16*)(W + 3 * SZ_ACT);
    u16* qkv  = (u16*)(W + 4 * SZ_ACT);                    // [b][n][768]
    u16* wfused = qkv;         // [8][512][1024] bf16, dead before qkv is written
    u16* pbuf = (u16*)(W + 4 * SZ_ACT + (size_t)NB * NPIX * 768 * 2);   // [8][N][N] bf16
    char* SM = (char*)(pbuf + (size_t)NB * NPIX * NPIX);
    float* logits = (float*)SM; SM += (size_t)NB * NPIX * 4;  // zero region start
    float* colsum = (float*)SM; SM += (size_t)NB * NPIX * 4;
    float* ctxb   = (float*)SM; SM += (size_t)NB * NCH * 4;
    float* ctx2b  = (float*)SM; SM += (size_t)NB * NCH * 4;   // zero region end
    float* maskb  = (float*)SM; SM += (size_t)NB * NPIX * 4;
    float* mxb    = (float*)SM; SM += (size_t)NB * NPIX * 4;
    float* invSb  = (float*)SM; SM += (size_t)NB * NPIX * 4;
    float* softb  = (float*)SM; SM += (size_t)NB * NPIX * 4;
    float* mulb   = (float*)SM; SM += (size_t)NB * NCH * 4;
    float* addb   = (float*)SM; SM += (size_t)NB * NCH * 4;
    float* zbuf   = (float*)SM; SM += (size_t)NB * NCH * 4;
    float* fbias  = (float*)SM; SM += (size_t)NB * NCH * 4;
    float* hnb    = (float*)SM; SM += (size_t)2 * NB * 128 * 4;
    float* wfold  = (float*)SM; SM += (size_t)9 * NCH * 4;
    u16* w1b   = (u16*)SM; SM += (size_t)512 * 512 * 2;
    u16* fuwb  = (u16*)SM; SM += (size_t)512 * 1024 * 2;
    u16* finwb = (u16*)SM; SM += (size_t)512 * 1024 * 2;
    u16* qkvwb = (u16*)SM; SM += (size_t)768 * 512 * 2;
    u16* w3t   = (u16*)SM; SM += (size_t)512 * 512 * 2;

    const float invs  = 0.99999500003749978f;   // 1/sqrt(1+1e-5)
    const float rs128 = 0.08838834764831845f;   // 1/sqrt(128)
    const long SACT = (long)NPIX * NCH;

    // zero logits/colsum/ctx/ctx2 first (logits accumulated by atomics)
    hipMemsetAsync(logits, 0,
        ((size_t)2 * NB * NPIX + (size_t)2 * NB * NCH) * 4, stream);
    // weight conversions in one dispatch
    prep_weights<<<1683, 256, 0, stream>>>(lb_w1, fu_w, fin_w, q_w, k_w, v_w,
        lb_w2, lb_g2, w1b, fuwb, finwb, qkvwb, wfold);
    transpose_cvt_ml<<<dim3(36, 8, 8), 256, 0, stream>>>(x, cm_w, xb, logits);
    transpose_w3<<<dim3(8, 8), 256, 0, stream>>>(lb_w3, lb_g3, w3t);

    // W'' = (fu_local . diag(g3*invs)) @ w3  -> wfused[:, :512] (8 replicas)
    mfma_gemm<<<dim3(4, 4, 8), 256, 0, stream>>>(w3t, 512, 0, fuwb, nullptr, 1024, 0,
        wfused, 1024, 524288, nullptr, nullptr, nullptr, 0, nullptr, 0, 512, 1.0f, 0);

    // local branch start: t1 = relu(bn(W1 @ x)); t2 = relu(bn(dw3x3(t1)))
    mfma_gemm<<<dim3(18, 4, 8), 256, 0, stream>>>(w1b, 512, 0, xb, nullptr, 512, SACT,
        bufA, 512, SACT, lb_g1, lb_b1, nullptr, 0, nullptr, 0, 512, invs, 1);
    dwconv_k<<<9216, 256, 0, stream>>>(bufA, wfold, lb_b2, bufB);
    // ContextBlock
    softmax_mask<<<8, 256, 0, stream>>>(logits, maskb);
    ctx_pool_k<<<dim3(18, 8), 512, 0, stream>>>(xb, maskb, ctxb);
    chan_h<<<512, 256, 0, stream>>>(ctxb, cmu_w1, cmu_b1, ca_w1, ca_b1, hnb);
    chan_ln<<<dim3(2, 8), 128, 0, stream>>>(cmu_lg, cmu_lb, ca_lg, ca_lb, hnb);
    chan_o<<<dim3(4, 2, 8), 128, 0, stream>>>(hnb, cmu_w2, cmu_b2, ca_w2, ca_b2, mulb, addb);
    // per-batch glob weights + fused bias
    scale_wglob<<<2048, 256, 0, stream>>>(fu_w, mulb, wfused);
    fuse_bias<<<dim3(2, 8), 256, 0, stream>>>(fu_w, fu_b, lb_b3, addb, fbias);
    // fused gx GEMM: gx = W''@t2 + (fu_glob.mul_b)@x + fbias
    mfma_gemm<<<dim3(18, 4, 8), 256, 0, stream>>>(wfused, 1024, 524288, bufB, xb, 512, SACT,
        gx, 512, SACT, nullptr, nullptr, nullptr, 0, fbias, 512, 1024, 1.0f, 0);
    // q|k|v stacked projection (overwrites wfused region - wfused is dead)
    mfma_gemm<<<dim3(18, 6, 8), 256, 0, stream>>>(qkvwb, 512, 0, gx, nullptr, 512, SACT,
        qkv, 768, (long)NPIX * 768, nullptr, nullptr, nullptr, 0, nullptr, 0, 512, 1.0f, 0);
    // attention: single 8-batch pass
    mfma_gemm<<<dim3(18, 18, 8), 256, 0, stream>>>(qkv + 128, 768, (long)NPIX * 768,
        qkv, nullptr, 768, (long)NPIX * 768,
        pbuf, NPIX, (long)NPIX * NPIX, nullptr, nullptr, nullptr, 0, nullptr, 0,
        128, rs128, 0);
    softmax_topk_wave<<<dim3(576, 8), 256, 0, stream>>>(pbuf, mxb, invSb, softb);
    colsum_k<<<dim3(9, 32, 8), 256, 0, stream>>>(pbuf, mxb, invSb, colsum);
    // epilogue path
    ctx2_pool_k<<<dim3(18, 8), 512, 0, stream>>>(qkv, colsum, softb, ctx2b);
    compute_z<<<dim3(2, 8), 256, 0, stream>>>(fin_w, ctx2b, zbuf);
    mfma_gemm<<<dim3(4, 18, 8), 256, 0, stream>>>(gx, 512, SACT, finwb, nullptr, 1024, 0,
        d_out, NPIX, (long)NCH * NPIX, nullptr, nullptr, zbuf, 512, nullptr, 0,
        512, 1.0f, 2);
}

// Round 13
// 385.578 us; speedup vs baseline: 1.0507x; 1.0017x over previous
//
#include <hip/hip_runtime.h>
#include <math.h>

#define NPIX 2304
#define NCH  512
#define NB   8
#define KNUM 230

typedef unsigned short u16;
typedef __attribute__((ext_vector_type(8))) short short8v;
typedef __attribute__((ext_vector_type(4))) float float4v;

__device__ __forceinline__ float bf2f(u16 u) {
    union { unsigned v; float f; } x; x.v = ((unsigned)u) << 16; return x.f;
}
__device__ __forceinline__ u16 f2bf(float f) {
    union { float f; unsigned v; } x; x.f = f;
    unsigned r = x.v + 0x7FFFu + ((x.v >> 16) & 1u);   // RNE
    return (u16)(r >> 16);
}

// ---------------- reductions ----------------
__device__ __forceinline__ float waveSum(float v) {
    #pragma unroll
    for (int o = 32; o > 0; o >>= 1) v += __shfl_down(v, o);
    return v;
}
__device__ __forceinline__ float blockSum256(float v, float* sc4) {
    v = waveSum(v);
    __syncthreads();
    if ((threadIdx.x & 63) == 0) sc4[threadIdx.x >> 6] = v;
    __syncthreads();
    return sc4[0] + sc4[1] + sc4[2] + sc4[3];
}
__device__ __forceinline__ float waveMaxF(float v) {
    #pragma unroll
    for (int o = 32; o > 0; o >>= 1) v = fmaxf(v, __shfl_down(v, o));
    return v;
}
__device__ __forceinline__ float blockMax256(float v, float* sc4) {
    v = waveMaxF(v);
    __syncthreads();
    if ((threadIdx.x & 63) == 0) sc4[threadIdx.x >> 6] = v;
    __syncthreads();
    return fmaxf(fmaxf(sc4[0], sc4[1]), fmaxf(sc4[2], sc4[3]));
}

// ---------------- async global->LDS 16B ----------------
__device__ __forceinline__ void gl_lds16(const u16* g, u16* l) {
    __builtin_amdgcn_global_load_lds(
        reinterpret_cast<const unsigned __attribute__((address_space(1)))*>(
            reinterpret_cast<uintptr_t>(g)),
        reinterpret_cast<unsigned __attribute__((address_space(3)))*>(
            reinterpret_cast<uintptr_t>(l)),
        16, 0, 0);
}

// ---------------- bf16 MFMA GEMM ----------------
// D[R, Cl] = alpha*scaleR[R]*sum_k A[R,k]*B[Cl,k] + biasR[R] + biasC[b,Cl] + biasRB[b,R]
// A, B row-major, k contiguous. Output stored out[b][Cl][R] (R contiguous).
// flags: 1 = relu, 2 = fp32 output (else bf16). B1: source for k >= 512 (concat).
__global__ __launch_bounds__(256, 3) void mfma_gemm(
    const u16* __restrict__ A, int ldA, long sA,
    const u16* __restrict__ B0, const u16* __restrict__ B1, int ldB, long sB,
    void* __restrict__ outp, int ldO, long sO,
    const float* __restrict__ scaleR, const float* __restrict__ biasR,
    const float* __restrict__ biasC, int ldbc,
    const float* __restrict__ biasRB, int ldrb,
    int K, float alpha, int flags)
{
    __shared__ u16 lA[128 * 64];
    __shared__ u16 lB[128 * 64];
    const int t  = threadIdx.x;
    const int w  = t >> 6, l = t & 63;
    const int wR = w >> 1, wC = w & 1;
    const int lg = l >> 4, lr = l & 15, l7 = l & 7;
    const int b   = blockIdx.z;
    const int Cl0 = blockIdx.x * 128;
    const int R0  = blockIdx.y * 128;
    const u16* Ab  = A + (size_t)b * sA;
    const u16* B0b = B0 + (size_t)b * sB;
    const u16* B1b = B1 ? B1 + (size_t)b * sB : nullptr;

    float4v acc[4][4];
    const float4v zero = {0.f, 0.f, 0.f, 0.f};
    #pragma unroll
    for (int i = 0; i < 4; ++i)
        #pragma unroll
        for (int j = 0; j < 4; ++j) acc[i][j] = zero;

    const int sr = t >> 3;     // staging row-in-issue (0..31)
    const int sp = t & 7;      // physical 16B chunk

    for (int k0 = 0; k0 < K; k0 += 64) {
        const u16* Bsrc = B0b; int kb = k0;
        if (B1b && k0 >= 512) { Bsrc = B1b; kb = k0 - 512; }
        #pragma unroll
        for (int i = 0; i < 4; ++i) {
            const int r  = i * 32 + sr;
            const int ca = sp ^ (r & 7);                  // pre-swizzled source chunk
            gl_lds16(Ab   + (size_t)(R0  + r) * ldA + (k0 + ca * 8), &lA[i * 2048 + t * 8]);
            gl_lds16(Bsrc + (size_t)(Cl0 + r) * ldB + (kb + ca * 8), &lB[i * 2048 + t * 8]);
        }
        __syncthreads();
        #pragma unroll
        for (int kk = 0; kk < 2; ++kk) {
            short8v af[4], bfv[4];
            const int p = (kk * 4 + lg) ^ l7;             // swizzled read chunk
            #pragma unroll
            for (int mt = 0; mt < 4; ++mt) {
                const int rA = wR * 64 + mt * 16 + lr;
                af[mt]  = *reinterpret_cast<const short8v*>(&lA[rA * 64 + p * 8]);
                const int rB = wC * 64 + mt * 16 + lr;
                bfv[mt] = *reinterpret_cast<const short8v*>(&lB[rB * 64 + p * 8]);
            }
            #pragma unroll
            for (int mt = 0; mt < 4; ++mt)
                #pragma unroll
                for (int nt = 0; nt < 4; ++nt)
                    acc[mt][nt] = __builtin_amdgcn_mfma_f32_16x16x32_bf16(
                        af[mt], bfv[nt], acc[mt][nt], 0, 0, 0);
        }
        __syncthreads();
    }

    const bool relu = (flags & 1), f32o = (flags & 2);
    #pragma unroll
    for (int nt = 0; nt < 4; ++nt) {
        const int Cl = Cl0 + wC * 64 + nt * 16 + lr;
        const float bc = biasC ? biasC[(size_t)b * ldbc + Cl] : 0.f;
        #pragma unroll
        for (int mt = 0; mt < 4; ++mt) {
            const int Rb = R0 + wR * 64 + mt * 16 + lg * 4;
            float4 scv = scaleR ? *reinterpret_cast<const float4*>(&scaleR[Rb])
                                : make_float4(1.f, 1.f, 1.f, 1.f);
            float4 bv  = biasR  ? *reinterpret_cast<const float4*>(&biasR[Rb])
                                : make_float4(0.f, 0.f, 0.f, 0.f);
            float4 rbv = biasRB ? *reinterpret_cast<const float4*>(&biasRB[(size_t)b * ldrb + Rb])
                                : make_float4(0.f, 0.f, 0.f, 0.f);
            float vals[4];
            #pragma unroll
            for (int j = 0; j < 4; ++j) {
                const float sc = alpha * ((&scv.x)[j]);
                float v = acc[mt][nt][j] * sc + (&bv.x)[j] + bc + (&rbv.x)[j];
                if (relu) v = fmaxf(v, 0.f);
                vals[j] = v;
            }
            if (f32o) {
                float* op = (float*)outp + (size_t)b * sO + (size_t)Cl * ldO + Rb;
                *reinterpret_cast<float4*>(op) = make_float4(vals[0], vals[1], vals[2], vals[3]);
            } else {
                ushort4 u;
                u.x = f2bf(vals[0]); u.y = f2bf(vals[1]);
                u.z = f2bf(vals[2]); u.w = f2bf(vals[3]);
                u16* op = (u16*)outp + (size_t)b * sO + (size_t)Cl * ldO + Rb;
                *reinterpret_cast<ushort4*>(op) = u;
            }
        }
    }
}

// ---------------- transpose+convert x + fused mask-logit partial dot ----------------
__global__ __launch_bounds__(256) void transpose_cvt_ml(
    const float* __restrict__ x, const float* __restrict__ cmw,
    u16* __restrict__ xb, float* __restrict__ logits)
{
    __shared__ float tile[64][65];
    const int t = threadIdx.x;
    const int n0 = blockIdx.x * 64, c0 = blockIdx.y * 64, b = blockIdx.z;
    const int tr = t >> 4, tc4 = (t & 15) * 4;
    #pragma unroll
    for (int i = 0; i < 4; ++i) {
        const int cc = tr + i * 16;
        float4 v = *reinterpret_cast<const float4*>(
            x + ((size_t)(b * NCH + c0 + cc)) * NPIX + n0 + tc4);
        tile[cc][tc4 + 0] = v.x; tile[cc][tc4 + 1] = v.y;
        tile[cc][tc4 + 2] = v.z; tile[cc][tc4 + 3] = v.w;
    }
    __syncthreads();
    #pragma unroll
    for (int i = 0; i < 4; ++i) {
        const int nn = tr + i * 16;
        ushort4 u;
        u.x = f2bf(tile[tc4 + 0][nn]); u.y = f2bf(tile[tc4 + 1][nn]);
        u.z = f2bf(tile[tc4 + 2][nn]); u.w = f2bf(tile[tc4 + 3][nn]);
        *reinterpret_cast<ushort4*>(xb + ((size_t)b * NPIX + n0 + nn) * NCH + c0 + tc4) = u;
    }
    const int nl = t >> 2, q = t & 3;
    float s = 0.f;
    #pragma unroll
    for (int k = 0; k < 16; ++k) {
        const int cc = q * 16 + k;
        s = fmaf(tile[cc][nl], cmw[c0 + cc], s);
    }
    s += __shfl_xor(s, 1);
    s += __shfl_xor(s, 2);
    if (q == 0) atomicAdd(&logits[(size_t)b * NPIX + n0 + nl], s);
}

// ---------------- w3T scaled: w3t[k][c] = lb_w3[c][k] * g3[c] * invs, bf16 ----------------
__global__ __launch_bounds__(256) void transpose_w3(
    const float* __restrict__ w3, const float* __restrict__ g3, u16* __restrict__ w3t)
{
    __shared__ float tile[64][65];
    const int t = threadIdx.x;
    const int k0 = blockIdx.x * 64, c0 = blockIdx.y * 64;
    const int tr = t >> 4, tc4 = (t & 15) * 4;
    #pragma unroll
    for (int i = 0; i < 4; ++i) {
        const int cc = tr + i * 16;
        const float s = g3[c0 + cc] * 0.99999500003749978f;
        float4 v = *reinterpret_cast<const float4*>(&w3[(size_t)(c0 + cc) * 512 + k0 + tc4]);
        tile[cc][tc4 + 0] = v.x * s; tile[cc][tc4 + 1] = v.y * s;
        tile[cc][tc4 + 2] = v.z * s; tile[cc][tc4 + 3] = v.w * s;
    }
    __syncthreads();
    #pragma unroll
    for (int i = 0; i < 4; ++i) {
        const int kk = tr + i * 16;
        ushort4 u;
        u.x = f2bf(tile[tc4 + 0][kk]); u.y = f2bf(tile[tc4 + 1][kk]);
        u.z = f2bf(tile[tc4 + 2][kk]); u.w = f2bf(tile[tc4 + 3][kk]);
        *reinterpret_cast<ushort4*>(&w3t[(size_t)(k0 + kk) * 512 + c0 + tc4]) = u;
    }
}

// ---------------- all weight conversions in one dispatch ----------------
__device__ __forceinline__ void cvt4(const float* s, u16* d, int i) {
    float4 v = reinterpret_cast<const float4*>(s)[i];
    ushort4 u; u.x = f2bf(v.x); u.y = f2bf(v.y); u.z = f2bf(v.z); u.w = f2bf(v.w);
    reinterpret_cast<ushort4*>(d)[i] = u;
}
__global__ __launch_bounds__(256) void prep_weights(
    const float* __restrict__ w1, const float* __restrict__ fu,
    const float* __restrict__ fin, const float* __restrict__ qw,
    const float* __restrict__ kw, const float* __restrict__ vw,
    const float* __restrict__ dww, const float* __restrict__ dwg,
    u16* __restrict__ w1b, u16* __restrict__ fuwb, u16* __restrict__ finwb,
    u16* __restrict__ qkvwb, float* __restrict__ wfold)
{
    const int i = blockIdx.x * 256 + threadIdx.x;
    if (i < 65536)            cvt4(w1, w1b, i);
    else if (i < 196608)      cvt4(fu, fuwb, i - 65536);
    else if (i < 327680)      cvt4(fin, finwb, i - 196608);
    else if (i < 344064)      cvt4(qw, qkvwb, i - 327680);
    else if (i < 360448)      cvt4(kw, qkvwb + 128 * 512, i - 344064);
    else if (i < 425984)      cvt4(vw, qkvwb + 256 * 512, i - 360448);
    else if (i < 425984 + 4608) {
        const int j = i - 425984;
        const int c = j / 9, tap = j % 9;
        wfold[tap * NCH + c] = dww[j] * dwg[c] * 0.99999500003749978f;
    }
}

// ---------------- depthwise 3x3 + BN + ReLU, [n][c] bf16 ----------------
__global__ __launch_bounds__(256) void dwconv_k(
    const u16* __restrict__ t1, const float* __restrict__ wf,
    const float* __restrict__ b2, u16* __restrict__ t2)
{
    const int idx = blockIdx.x * 256 + threadIdx.x;
    const int cq = idx & 127;
    const int n  = (idx >> 7) % NPIX;
    const int b  = (idx >> 7) / NPIX;
    const int c  = cq * 4;
    const int y = n / 48, x = n % 48;
    float s0 = 0.f, s1 = 0.f, s2 = 0.f, s3 = 0.f;
    #pragma unroll
    for (int dy = -1; dy <= 1; ++dy) {
        const int yy = y + dy;
        if (yy < 0 || yy >= 48) continue;
        #pragma unroll
        for (int dx = -1; dx <= 1; ++dx) {
            const int xx = x + dx;
            if (xx < 0 || xx >= 48) continue;
            ushort4 tv = *reinterpret_cast<const ushort4*>(
                &t1[((size_t)b * NPIX + yy * 48 + xx) * NCH + c]);
            float4 wv = *reinterpret_cast<const float4*>(
                &wf[((dy + 1) * 3 + dx + 1) * NCH + c]);
            s0 = fmaf(bf2f(tv.x), wv.x, s0); s1 = fmaf(bf2f(tv.y), wv.y, s1);
            s2 = fmaf(bf2f(tv.z), wv.z, s2); s3 = fmaf(bf2f(tv.w), wv.w, s3);
        }
    }
    float4 bb = *reinterpret_cast<const float4*>(&b2[c]);
    ushort4 o;
    o.x = f2bf(fmaxf(s0 + bb.x, 0.f)); o.y = f2bf(fmaxf(s1 + bb.y, 0.f));
    o.z = f2bf(fmaxf(s2 + bb.z, 0.f)); o.w = f2bf(fmaxf(s3 + bb.w, 0.f));
    *reinterpret_cast<ushort4*>(&t2[((size_t)b * NPIX + n) * NCH + c]) = o;
}

// ---------------- ContextBlock ----------------
__global__ __launch_bounds__(256) void softmax_mask(
    const float* __restrict__ logits, float* __restrict__ mask)
{
    __shared__ float sc[4];
    const int b = blockIdx.x, t = threadIdx.x;
    const float* lr = logits + (size_t)b * NPIX;
    float mx = -3.4e38f;
    for (int i = t; i < NPIX; i += 256) mx = fmaxf(mx, lr[i]);
    mx = blockMax256(mx, sc);
    float s = 0.f;
    for (int i = t; i < NPIX; i += 256) s += __expf(lr[i] - mx);
    s = blockSum256(s, sc);
    const float inv = 1.0f / s;
    for (int i = t; i < NPIX; i += 256) mask[(size_t)b * NPIX + i] = __expf(lr[i] - mx) * inv;
}

__global__ __launch_bounds__(512) void ctx_pool_k(
    const u16* __restrict__ xb, const float* __restrict__ mask, float* __restrict__ ctx)
{
    const int c = threadIdx.x, b = blockIdx.y;
    const int nn0 = blockIdx.x * 128;
    float s = 0.f;
    for (int n = nn0; n < nn0 + 128; ++n)
        s = fmaf(bf2f(xb[((size_t)b * NPIX + n) * NCH + c]), mask[(size_t)b * NPIX + n], s);
    atomicAdd(&ctx[b * NCH + c], s);
}

// ---------------- channel MLP: 3 stages, wave-per-dot parallelism ----------------
__global__ __launch_bounds__(256) void chan_h(
    const float* __restrict__ ctxv,
    const float* __restrict__ mw1, const float* __restrict__ mb1,
    const float* __restrict__ aw1, const float* __restrict__ ab1,
    float* __restrict__ hnb)
{
    const int w = threadIdx.x >> 6, l = threadIdx.x & 63;
    const int gid = blockIdx.x * 4 + w;          // 0..2047
    const int path = gid >> 10;
    const int rem  = gid & 1023;
    const int h = rem >> 3, b = rem & 7;
    const float* W1 = path ? aw1 : mw1;
    const float* B1 = path ? ab1 : mb1;
    const float4 wa = *reinterpret_cast<const float4*>(&W1[h * 512 + l * 8]);
    const float4 wb = *reinterpret_cast<const float4*>(&W1[h * 512 + l * 8 + 4]);
    const float4 ca = *reinterpret_cast<const float4*>(&ctxv[b * 512 + l * 8]);
    const float4 cb = *reinterpret_cast<const float4*>(&ctxv[b * 512 + l * 8 + 4]);
    float s = wa.x * ca.x + wa.y * ca.y + wa.z * ca.z + wa.w * ca.w
            + wb.x * cb.x + wb.y * cb.y + wb.z * cb.z + wb.w * cb.w;
    s = waveSum(s);
    if (l == 0) hnb[(path * 8 + b) * 128 + h] = s + B1[h];
}

__global__ __launch_bounds__(128) void chan_ln(
    const float* __restrict__ mlg, const float* __restrict__ mlb,
    const float* __restrict__ alg, const float* __restrict__ alb,
    float* __restrict__ hnb)
{
    __shared__ float sc[2];
    const int path = blockIdx.x, b = blockIdx.y, t = threadIdx.x;
    float* hp = hnb + (path * 8 + b) * 128;
    const float v = hp[t];
    float s1 = waveSum(v);
    if ((t & 63) == 0) sc[t >> 6] = s1;
    __syncthreads();
    const float mu = (sc[0] + sc[1]) * (1.0f / 128.0f);
    const float d = v - mu;
    float s2 = waveSum(d * d);
    __syncthreads();
    if ((t & 63) == 0) sc[t >> 6] = s2;
    __syncthreads();
    const float var = (sc[0] + sc[1]) * (1.0f / 128.0f);
    const float* LG = path ? alg : mlg;
    const float* LB = path ? alb : mlb;
    hp[t] = fmaxf(d / sqrtf(var + 1e-5f) * LG[t] + LB[t], 0.f);
}

__global__ __launch_bounds__(128) void chan_o(
    const float* __restrict__ hnb,
    const float* __restrict__ mw2, const float* __restrict__ mb2,
    const float* __restrict__ aw2, const float* __restrict__ ab2,
    float* __restrict__ mulo, float* __restrict__ addo)
{
    __shared__ float hs[128];
    const int oc = blockIdx.x, path = blockIdx.y, b = blockIdx.z;
    const int t = threadIdx.x;
    hs[t] = hnb[(path * 8 + b) * 128 + t];
    __syncthreads();
    const int o = oc * 128 + t;
    const float* W2 = path ? aw2 : mw2;
    float s = (path ? ab2 : mb2)[o];
    #pragma unroll
    for (int p = 0; p < 128; p += 4) {
        const float4 wv = *reinterpret_cast<const float4*>(&W2[o * 128 + p]);
        s += wv.x * hs[p] + wv.y * hs[p + 1] + wv.z * hs[p + 2] + wv.w * hs[p + 3];
    }
    if (path == 0) mulo[b * 512 + o] = 1.0f / (1.0f + __expf(-s));
    else           addo[b * 512 + o] = s;
}

// ---------------- per-batch glob weights ----------------
__global__ __launch_bounds__(256) void scale_wglob(
    const float* __restrict__ fuw, const float* __restrict__ mulv, u16* __restrict__ wf)
{
    const int idx = blockIdx.x * 256 + threadIdx.x;   // 8*512*128
    const int cq = idx & 127;
    const int o  = (idx >> 7) & 511;
    const int b  = idx >> 16;
    const int c  = cq * 4;
    float4 w = *reinterpret_cast<const float4*>(&fuw[(size_t)o * 1024 + 512 + c]);
    float4 m = *reinterpret_cast<const float4*>(&mulv[b * 512 + c]);
    ushort4 u;
    u.x = f2bf(w.x * m.x); u.y = f2bf(w.y * m.y);
    u.z = f2bf(w.z * m.z); u.w = f2bf(w.w * m.w);
    *reinterpret_cast<ushort4*>(&wf[(size_t)b * 524288 + (size_t)o * 1024 + 512 + c]) = u;
}

// fb[b][o] = fu_b[o] + sum_c fu_w[o,c]*b3[c] + sum_c fu_w[o,512+c]*add[b,c]
__global__ __launch_bounds__(256) void fuse_bias(
    const float* __restrict__ fuw, const float* __restrict__ fub,
    const float* __restrict__ b3, const float* __restrict__ addv, float* __restrict__ fb)
{
    const int o = blockIdx.x * 256 + threadIdx.x;     // grid.x = 2
    const int b = blockIdx.y;
    const float* wr = fuw + (size_t)o * 1024;
    float s = fub[o];
    for (int c = 0; c < 512; c += 4) {
        float4 w1 = *reinterpret_cast<const float4*>(&wr[c]);
        float4 bv = *reinterpret_cast<const float4*>(&b3[c]);
        float4 w2 = *reinterpret_cast<const float4*>(&wr[512 + c]);
        float4 av = *reinterpret_cast<const float4*>(&addv[b * 512 + c]);
        s += w1.x * bv.x + w1.y * bv.y + w1.z * bv.z + w1.w * bv.w
           + w2.x * av.x + w2.y * av.y + w2.z * av.z + w2.w * av.w;
    }
    fb[b * 512 + o] = s;
}

// ---------------- wave-per-row softmax + exact top-k on bf16 keys ----------------
// Plain ballot counting (measured best), with exact kmax-prefix pruning: any
// candidate with cand > kmax has count(>=cand) == 0 < KNUM, so the bit stays 0
// and the 36 ballots for that iteration are skipped (wave-uniform branch).
__global__ __launch_bounds__(256) void softmax_topk_wave(
    const u16* __restrict__ p, float* __restrict__ mxo,
    float* __restrict__ invSo, float* __restrict__ softo)
{
    const int w = threadIdx.x >> 6, l = threadIdx.x & 63;
    const int r = blockIdx.x * 4 + w;
    const int bc = blockIdx.y;
    const u16* pr = p + ((size_t)bc * NPIX + r) * NPIX;
    const uint4* p16 = reinterpret_cast<const uint4*>(pr);
    uint4 q0 = p16[l], q1 = p16[64 + l], q2 = p16[128 + l], q3 = p16[192 + l];
    uint2 q4 = reinterpret_cast<const uint2*>(pr)[512 + l];
    unsigned uw[18] = {q0.x, q0.y, q0.z, q0.w, q1.x, q1.y, q1.z, q1.w,
                       q2.x, q2.y, q2.z, q2.w, q3.x, q3.y, q3.z, q3.w,
                       q4.x, q4.y};
    unsigned km[36];
    #pragma unroll
    for (int i = 0; i < 18; ++i) {
        const unsigned v = uw[i];
        const unsigned m = ((v >> 15) & 0x10001u) * 0x7FFFu + 0x80008000u;
        const unsigned s = v ^ m;           // two sortable keys packed
        km[2 * i]     = s & 0xFFFFu;
        km[2 * i + 1] = s >> 16;
    }
    unsigned kmax = km[0];
    #pragma unroll
    for (int i = 1; i < 36; ++i) kmax = max(kmax, km[i]);
    #pragma unroll
    for (int o = 32; o > 0; o >>= 1) kmax = max(kmax, (unsigned)__shfl_xor((int)kmax, o));
    const unsigned mxbits = (kmax & 0x8000u) ? (kmax ^ 0x8000u) : (kmax ^ 0xFFFFu);
    const float mx = bf2f((u16)mxbits);
    unsigned kt = 0u;
    for (int bit = 15; bit >= 0; --bit) {
        const unsigned cand = kt | (1u << bit);
        if (cand > kmax) continue;          // count == 0 < KNUM: bit stays 0, skip ballots
        int c = 0;
        #pragma unroll
        for (int i = 0; i < 36; ++i)
            c += (int)__popcll(__ballot(km[i] >= cand));
        if (c >= KNUM) kt = cand;
    }
    const unsigned tbits = (kt & 0x8000u) ? (kt ^ 0x8000u) : (kt ^ 0xFFFFu);
    const float te = __expf(bf2f((u16)tbits) - mx);
    float S = 0.f, ss = 0.f; int a = 0;
    #pragma unroll
    for (int i = 0; i < 36; ++i) {
        const unsigned bb = (km[i] & 0x8000u) ? (km[i] ^ 0x8000u) : (km[i] ^ 0xFFFFu);
        const float e = __expf(bf2f((u16)bb) - mx);
        S += e;
        const bool gt = km[i] > kt;
        if (gt) ss += e;
        a += (int)__popcll(__ballot(gt));
    }
    #pragma unroll
    for (int o = 32; o > 0; o >>= 1) { S += __shfl_xor(S, o); ss += __shfl_xor(ss, o); }
    if (l == 0) {
        const size_t gi = (size_t)bc * NPIX + r;
        mxo[gi] = mx; invSo[gi] = 1.0f / S;
        softo[gi] = (ss + (float)(KNUM - a) * te) / (S * (float)KNUM);
    }
}

// colsum[b][j] = sum_i exp(p[i][j]-mx[i]) * invS[i]; i split 32 ways for occupancy.
__global__ __launch_bounds__(256) void colsum_k(
    const u16* __restrict__ p, const float* __restrict__ mxo,
    const float* __restrict__ invSo, float* __restrict__ colsum)
{
    const int j = blockIdx.x * 256 + threadIdx.x;
    const int ic0 = blockIdx.y * 72;
    const int bc = blockIdx.z;
    const float* mxr = mxo + (size_t)bc * NPIX;
    const float* isr = invSo + (size_t)bc * NPIX;
    const u16* pb = p + (size_t)bc * NPIX * NPIX;
    float s = 0.f;
    #pragma unroll 4
    for (int i = ic0; i < ic0 + 72; ++i)
        s += __expf(bf2f(pb[(size_t)i * NPIX + j]) - mxr[i]) * isr[i];
    atomicAdd(&colsum[(size_t)bc * NPIX + j], s);
}

__global__ __launch_bounds__(512) void ctx2_pool_k(
    const u16* __restrict__ qkv, const float* __restrict__ colsum,
    const float* __restrict__ soft, float* __restrict__ ctx2)
{
    const int c = threadIdx.x, b = blockIdx.y;
    const int nn0 = blockIdx.x * 128;
    float s = 0.f;
    for (int n = nn0; n < nn0 + 128; ++n) {
        const float wgt = colsum[(size_t)b * NPIX + n] * soft[(size_t)b * NPIX + n];
        s = fmaf(bf2f(qkv[((size_t)b * NPIX + n) * 768 + 256 + c]), wgt, s);
    }
    atomicAdd(&ctx2[b * NCH + c], s * (1.0f / (float)NPIX));
}

__global__ __launch_bounds__(256) void compute_z(
    const float* __restrict__ finw, const float* __restrict__ ctx2, float* __restrict__ z)
{
    const int o = blockIdx.x * 256 + threadIdx.x;
    const int b = blockIdx.y;
    const float* c2 = ctx2 + b * NCH;
    const float* wr = finw + (size_t)o * 1024 + 512;
    float s = 0.f;
    for (int c = 0; c < NCH; ++c) s = fmaf(wr[c], c2[c], s);
    z[b * NCH + o] = s;
}

// ---------------- host launcher ----------------
extern "C" void kernel_launch(void* const* d_in, const int* in_sizes, int n_in,
                              void* d_out, int out_size, void* d_ws, size_t ws_size,
                              hipStream_t stream)
{
    (void)in_sizes; (void)n_in; (void)out_size; (void)ws_size;
    const float* x      = (const float*)d_in[0];
    const float* lb_w1  = (const float*)d_in[1];
    const float* lb_g1  = (const float*)d_in[2];
    const float* lb_b1  = (const float*)d_in[3];
    const float* lb_w2  = (const float*)d_in[4];
    const float* lb_g2  = (const float*)d_in[5];
    const float* lb_b2  = (const float*)d_in[6];
    const float* lb_w3  = (const float*)d_in[7];
    const float* lb_g3  = (const float*)d_in[8];
    const float* lb_b3  = (const float*)d_in[9];
    const float* cm_w   = (const float*)d_in[10];
    // cm_b (d_in[11]) unused: softmax is shift-invariant to a scalar logit bias
    const float* ca_w1  = (const float*)d_in[12];
    const float* ca_b1  = (const float*)d_in[13];
    const float* ca_lg  = (const float*)d_in[14];
    const float* ca_lb  = (const float*)d_in[15];
    const float* ca_w2  = (const float*)d_in[16];
    const float* ca_b2  = (const float*)d_in[17];
    const float* cmu_w1 = (const float*)d_in[18];
    const float* cmu_b1 = (const float*)d_in[19];
    const float* cmu_lg = (const float*)d_in[20];
    const float* cmu_lb = (const float*)d_in[21];
    const float* cmu_w2 = (const float*)d_in[22];
    const float* cmu_b2 = (const float*)d_in[23];
    const float* fu_w   = (const float*)d_in[24];
    const float* fu_b   = (const float*)d_in[25];
    // 26..37 dead (region == 1 identically)
    const float* q_w    = (const float*)d_in[38];
    const float* k_w    = (const float*)d_in[39];
    const float* v_w    = (const float*)d_in[40];
    const float* fin_w  = (const float*)d_in[41];

    char* W = (char*)d_ws;
    const size_t SZ_ACT = (size_t)NB * NPIX * NCH * 2;     // 18,874,368 B
    u16* xb   = (u16*)(W);
    u16* bufA = (u16*)(W + SZ_ACT);                        // t1
    u16* bufB = (u16*)(W + 2 * SZ_ACT);                    // t2
    u16* gx   = (u16*)(W + 3 * SZ_ACT);
    u16* qkv  = (u16*)(W + 4 * SZ_ACT);                    // [b][n][768]
    u16* wfused = qkv;         // [8][512][1024] bf16, dead before qkv is written
    u16* pbuf = (u16*)(W + 4 * SZ_ACT + (size_t)NB * NPIX * 768 * 2);   // [8][N][N] bf16
    char* SM = (char*)(pbuf + (size_t)NB * NPIX * NPIX);
    float* logits = (float*)SM; SM += (size_t)NB * NPIX * 4;  // zero region start
    float* colsum = (float*)SM; SM += (size_t)NB * NPIX * 4;
    float* ctxb   = (float*)SM; SM += (size_t)NB * NCH * 4;
    float* ctx2b  = (float*)SM; SM += (size_t)NB * NCH * 4;   // zero region end
    float* maskb  = (float*)SM; SM += (size_t)NB * NPIX * 4;
    float* mxb    = (float*)SM; SM += (size_t)NB * NPIX * 4;
    float* invSb  = (float*)SM; SM += (size_t)NB * NPIX * 4;
    float* softb  = (float*)SM; SM += (size_t)NB * NPIX * 4;
    float* mulb   = (float*)SM; SM += (size_t)NB * NCH * 4;
    float* addb   = (float*)SM; SM += (size_t)NB * NCH * 4;
    float* zbuf   = (float*)SM; SM += (size_t)NB * NCH * 4;
    float* fbias  = (float*)SM; SM += (size_t)NB * NCH * 4;
    float* hnb    = (float*)SM; SM += (size_t)2 * NB * 128 * 4;
    float* wfold  = (float*)SM; SM += (size_t)9 * NCH * 4;
    u16* w1b   = (u16*)SM; SM += (size_t)512 * 512 * 2;
    u16* fuwb  = (u16*)SM; SM += (size_t)512 * 1024 * 2;
    u16* finwb = (u16*)SM; SM += (size_t)512 * 1024 * 2;
    u16* qkvwb = (u16*)SM; SM += (size_t)768 * 512 * 2;
    u16* w3t   = (u16*)SM; SM += (size_t)512 * 512 * 2;

    const float invs  = 0.99999500003749978f;   // 1/sqrt(1+1e-5)
    const float rs128 = 0.08838834764831845f;   // 1/sqrt(128)
    const long SACT = (long)NPIX * NCH;

    // zero logits/colsum/ctx/ctx2 first (logits accumulated by atomics)
    hipMemsetAsync(logits, 0,
        ((size_t)2 * NB * NPIX + (size_t)2 * NB * NCH) * 4, stream);
    // weight conversions in one dispatch
    prep_weights<<<1683, 256, 0, stream>>>(lb_w1, fu_w, fin_w, q_w, k_w, v_w,
        lb_w2, lb_g2, w1b, fuwb, finwb, qkvwb, wfold);
    transpose_cvt_ml<<<dim3(36, 8, 8), 256, 0, stream>>>(x, cm_w, xb, logits);
    transpose_w3<<<dim3(8, 8), 256, 0, stream>>>(lb_w3, lb_g3, w3t);

    // W'' = (fu_local . diag(g3*invs)) @ w3  -> wfused[:, :512] (8 replicas)
    mfma_gemm<<<dim3(4, 4, 8), 256, 0, stream>>>(w3t, 512, 0, fuwb, nullptr, 1024, 0,
        wfused, 1024, 524288, nullptr, nullptr, nullptr, 0, nullptr, 0, 512, 1.0f, 0);

    // local branch start: t1 = relu(bn(W1 @ x)); t2 = relu(bn(dw3x3(t1)))
    mfma_gemm<<<dim3(18, 4, 8), 256, 0, stream>>>(w1b, 512, 0, xb, nullptr, 512, SACT,
        bufA, 512, SACT, lb_g1, lb_b1, nullptr, 0, nullptr, 0, 512, invs, 1);
    dwconv_k<<<9216, 256, 0, stream>>>(bufA, wfold, lb_b2, bufB);
    // ContextBlock
    softmax_mask<<<8, 256, 0, stream>>>(logits, maskb);
    ctx_pool_k<<<dim3(18, 8), 512, 0, stream>>>(xb, maskb, ctxb);
    chan_h<<<512, 256, 0, stream>>>(ctxb, cmu_w1, cmu_b1, ca_w1, ca_b1, hnb);
    chan_ln<<<dim3(2, 8), 128, 0, stream>>>(cmu_lg, cmu_lb, ca_lg, ca_lb, hnb);
    chan_o<<<dim3(4, 2, 8), 128, 0, stream>>>(hnb, cmu_w2, cmu_b2, ca_w2, ca_b2, mulb, addb);
    // per-batch glob weights + fused bias
    scale_wglob<<<2048, 256, 0, stream>>>(fu_w, mulb, wfused);
    fuse_bias<<<dim3(2, 8), 256, 0, stream>>>(fu_w, fu_b, lb_b3, addb, fbias);
    // fused gx GEMM: gx = W''@t2 + (fu_glob.mul_b)@x + fbias
    mfma_gemm<<<dim3(18, 4, 8), 256, 0, stream>>>(wfused, 1024, 524288, bufB, xb, 512, SACT,
        gx, 512, SACT, nullptr, nullptr, nullptr, 0, fbias, 512, 1024, 1.0f, 0);
    // q|k|v stacked projection (overwrites wfused region - wfused is dead)
    mfma_gemm<<<dim3(18, 6, 8), 256, 0, stream>>>(qkvwb, 512, 0, gx, nullptr, 512, SACT,
        qkv, 768, (long)NPIX * 768, nullptr, nullptr, nullptr, 0, nullptr, 0, 512, 1.0f, 0);
    // attention: single 8-batch pass
    mfma_gemm<<<dim3(18, 18, 8), 256, 0, stream>>>(qkv + 128, 768, (long)NPIX * 768,
        qkv, nullptr, 768, (long)NPIX * 768,
        pbuf, NPIX, (long)NPIX * NPIX, nullptr, nullptr, nullptr, 0, nullptr, 0,
        128, rs128, 0);
    softmax_topk_wave<<<dim3(576, 8), 256, 0, stream>>>(pbuf, mxb, invSb, softb);
    colsum_k<<<dim3(9, 32, 8), 256, 0, stream>>>(pbuf, mxb, invSb, colsum);
    // epilogue path
    ctx2_pool_k<<<dim3(18, 8), 512, 0, stream>>>(qkv, colsum, softb, ctx2b);
    compute_z<<<dim3(2, 8), 256, 0, stream>>>(fin_w, ctx2b, zbuf);
    mfma_gemm<<<dim3(4, 18, 8), 256, 0, stream>>>(gx, 512, SACT, finwb, nullptr, 1024, 0,
        d_out, NPIX, (long)NCH * NPIX, nullptr, nullptr, zbuf, 512, nullptr, 0,
        512, 1.0f, 2);
}